// Round 9
// baseline (1963.974 us; speedup 1.0000x reference)
//
#include <hip/hip_runtime.h>
#include <hip/hip_bf16.h>
#include <stdint.h>

// ---------------- problem constants ----------------
constexpr int E   = 384;
constexpr int DFF = 1536;
constexpr int NH  = 6;
constexpr int HD  = 64;
constexpr int T   = 256;
constexpr int NL  = 6;
constexpr int NV  = 65;
constexpr int BB  = 128;
constexpr int MTOT = BB * T;           // 32768 rows
constexpr int CB  = 32;                // (kept for ws layout compatibility)

typedef __bf16 bf16;
typedef __attribute__((ext_vector_type(8))) __bf16 bf16x8;
typedef __attribute__((ext_vector_type(4))) __bf16 bf16x4;
typedef __attribute__((ext_vector_type(4))) float floatx4;

// direct global->LDS DMA, 16B per lane (dest = wave-uniform base; HW adds lane*16)
__device__ __forceinline__ void gload_lds16(const void* g, void* l) {
    __builtin_amdgcn_global_load_lds(
        (const __attribute__((address_space(1))) void*)g,
        (__attribute__((address_space(3))) void*)l, 16, 0, 0);
}

// ================= v10: 8-phase 256x256 GEMM (template port) =================
// r0-r8 all shared ONE coarse phase per K-step -> ~20% MfmaUtil cap (the
// 2-phase structural stall, m233: 72% of period = stage+vmcnt+barrier).
// This is the verified 8-phase schedule: BK=64, 2 K-tiles per iteration,
// 8 phases; each phase = {ds_read quadrant | stage 1 chunk | barrier |
// lgkmcnt(0) | 16 MFMA | barrier}; vmcnt(0) only at the 2 half-iteration
// boundaries, each waiting loads issued 2-4 phases (~600+cyc) earlier.
// Buffer liveness: buf0 holds even tiles, buf1 odd. Tile t+1 staged PH0-1
// (into buf1, free since prev PH7 barrier), waited at PH3-end. Tile t+2
// staged PH4-5 (into buf0, free since PH3 barrier), waited at PH7-end.
// Geometry: 512 thr / 8 waves (wm 0..1 x wn 0..3); per-wave 128x64 out
// (acc[8][4] = 128 VGPR); LDS 2 x (A 32KB + B 32KB) = 128KB; 1 block/CU.
// A LDS: 2 k32-subs, rowpair*128B lines, XOR swizzle on GLOBAL source
// (linear DMA dest, rule-21; read-side same XOR; family verified 0-conflict
// r1-r8). B LDS: c16-group chunks, lane-linear (conflict-free).
// N without padding: overlapped last tile (n0 = min(nt*256, N-256)) +
// store mask colL >= sLo -> disjoint stores (safe for MODE1 accumulate).
// MODE 0: bf16 out (+bias,+relu) | MODE 1: residual += | MODE 5: QKV
// (nt<3 -> qk SWAP=1; nt>=3 -> vt SWAP=0).
#define SBUF8 65536

template <int MODE, int SWAP>
__device__ __forceinline__ void gemm8_body(
    char* L,
    const bf16* __restrict__ A, int lda,
    const bf16* __restrict__ Bf,
    const float* __restrict__ bias,
    void* __restrict__ Cv, void* __restrict__ Cv2, int ldc,
    int n0, int sLo, int mt, int Ncols, int K, int relu)
{
    int tid = threadIdx.x;
    int lane = tid & 63;
    int wid = tid >> 6;            // 0..7
    int wm = wid >> 2;             // 0..1  (row half)
    int wn = wid & 3;              // 0..3  (col quarter)
    int lq = lane >> 4, lr = lane & 15;

    const bf16* Ab = A + (long)mt * 256 * lda;
    int nks = K / 32;
    int NT  = K / 64;

    // ---- A staging map: chunk c = wid*2+l (1KB), rp = c*8 + (lane>>3),
    //      slot s = lane&7 holds source slot s^(rp&7) ----
    int l3 = lane >> 3;
    int sp = (lane & 7) ^ l3;
    int kO = (sp & 3) * 8;
    int rowA0 = (wid * 2 + 0) * 16 + 2 * l3 + (sp >> 2);
    int rowA1 = (wid * 2 + 1) * 16 + 2 * l3 + (sp >> 2);
    const bf16* srcA0 = Ab + (long)rowA0 * lda + kO;
    const bf16* srcA1 = Ab + (long)rowA1 * lda + kO;
    int dstA0 = (wid * 2 + 0) * 1024;     // + s*16384 for k32-sub s
    int dstA1 = (wid * 2 + 1) * 1024;

    // ---- B staging map: c16 group g = wid*2+l ----
    int c16b = n0 >> 4;
    const bf16* srcB0 = Bf + ((long)(c16b + wid * 2 + 0) * nks) * 512 + lane * 8;
    const bf16* srcB1 = Bf + ((long)(c16b + wid * 2 + 1) * nks) * 512 + lane * 8;
    int dstB0 = 32768 + (wid * 2 + 0) * 2048;   // + s*1024
    int dstB1 = 32768 + (wid * 2 + 1) * 2048;

    // ---- read-side offsets ----
    // A frag (mi, sub s): rp = wm*64 + mi*8 + (lr>>1); slot = ((lr&1)<<2|lq)^(rp&7)
    int aro = wm * 8192 + (lr >> 1) * 128 +
              (((((lr & 1) << 2) | lq) ^ ((lr >> 1) & 7)) << 4);
    // B frag (nf, s): group wn*4+nf
    int bro = 32768 + (wn * 4) * 2048 + lane * 16;

    floatx4 acc[8][4];
#pragma unroll
    for (int i = 0; i < 8; i++)
#pragma unroll
        for (int j = 0; j < 4; j++) acc[i][j] = floatx4{0.f, 0.f, 0.f, 0.f};

    bf16x8 af[4][2];
    bf16x8 bq[2][2][2];

#define STAGE_A8(KT, BO) { long ko_ = (long)(KT) * 64;                          \
    gload_lds16(srcA0 + ko_,      L + (BO) + dstA0);                            \
    gload_lds16(srcA0 + ko_ + 32, L + (BO) + 16384 + dstA0);                    \
    gload_lds16(srcA1 + ko_,      L + (BO) + dstA1);                            \
    gload_lds16(srcA1 + ko_ + 32, L + (BO) + 16384 + dstA1); }

#define STAGE_B8(KT, BO) {                                                      \
    gload_lds16(srcB0 + ((long)(KT) * 2    ) * 512, L + (BO) + dstB0);          \
    gload_lds16(srcB0 + ((long)(KT) * 2 + 1) * 512, L + (BO) + dstB0 + 1024);   \
    gload_lds16(srcB1 + ((long)(KT) * 2    ) * 512, L + (BO) + dstB1);          \
    gload_lds16(srcB1 + ((long)(KT) * 2 + 1) * 512, L + (BO) + dstB1 + 1024); }

#define LOAD_A8(MQ, BO) { _Pragma("unroll")                                     \
    for (int s_ = 0; s_ < 2; s_++) { _Pragma("unroll")                          \
      for (int m4_ = 0; m4_ < 4; m4_++)                                         \
        af[m4_][s_] = *(const bf16x8*)(L + (BO) + s_ * 16384 +                  \
                                       ((MQ) * 4 + m4_) * 1024 + aro); } }

#define LOAD_B8(NQ, BO) { _Pragma("unroll")                                     \
    for (int s_ = 0; s_ < 2; s_++) { _Pragma("unroll")                          \
      for (int n2_ = 0; n2_ < 2; n2_++)                                         \
        bq[NQ][n2_][s_] = *(const bf16x8*)(L + (BO) + bro +                     \
                                           ((NQ) * 2 + n2_) * 2048 + s_ * 1024); } }

#define QMFMA8(MQ, NQ) { _Pragma("unroll")                                      \
    for (int s_ = 0; s_ < 2; s_++) { _Pragma("unroll")                          \
      for (int m4_ = 0; m4_ < 4; m4_++) { _Pragma("unroll")                     \
        for (int n2_ = 0; n2_ < 2; n2_++) {                                     \
          if (SWAP)                                                             \
            acc[(MQ)*4+m4_][(NQ)*2+n2_] = __builtin_amdgcn_mfma_f32_16x16x32_bf16( \
                bq[NQ][n2_][s_], af[m4_][s_], acc[(MQ)*4+m4_][(NQ)*2+n2_], 0,0,0); \
          else                                                                  \
            acc[(MQ)*4+m4_][(NQ)*2+n2_] = __builtin_amdgcn_mfma_f32_16x16x32_bf16( \
                af[m4_][s_], bq[NQ][n2_][s_], acc[(MQ)*4+m4_][(NQ)*2+n2_], 0,0,0); } } } }

#define PH_SYNC { __builtin_amdgcn_s_barrier();                                 \
    asm volatile("s_waitcnt lgkmcnt(0)" ::: "memory");                          \
    __builtin_amdgcn_sched_barrier(0); }
#define VM0_ asm volatile("s_waitcnt vmcnt(0)" ::: "memory")

    // ---- prologue: stage tile0 -> buf0 ----
    STAGE_A8(0, 0); STAGE_B8(0, 0);
    VM0_;
    __builtin_amdgcn_s_barrier();

    int nit = NT >> 1;
    for (int it = 0; it < nit; ++it) {
        int t = it * 2;
        // ======== first half: tile t (buf0) ========
        // PH0: q(0,0); stage A of tile t+1 -> buf1
        LOAD_A8(0, 0); LOAD_B8(0, 0);
        STAGE_A8(t + 1, SBUF8);
        PH_SYNC;
        __builtin_amdgcn_s_setprio(1); QMFMA8(0, 0); __builtin_amdgcn_s_setprio(0);
        __builtin_amdgcn_s_barrier();
        // PH1: q(0,1); stage B of tile t+1 -> buf1
        LOAD_B8(1, 0);
        STAGE_B8(t + 1, SBUF8);
        PH_SYNC;
        __builtin_amdgcn_s_setprio(1); QMFMA8(0, 1); __builtin_amdgcn_s_setprio(0);
        __builtin_amdgcn_s_barrier();
        // PH2: q(1,0)
        LOAD_A8(1, 0);
        PH_SYNC;
        __builtin_amdgcn_s_setprio(1); QMFMA8(1, 0); __builtin_amdgcn_s_setprio(0);
        __builtin_amdgcn_s_barrier();
        // PH3: q(1,1); boundary wait (tile t+1 loads, issued PH0-1)
        __builtin_amdgcn_s_setprio(1); QMFMA8(1, 1); __builtin_amdgcn_s_setprio(0);
        VM0_;
        __builtin_amdgcn_s_barrier();
        // ======== second half: tile t+1 (buf1) ========
        // PH4: q(0,0); stage A of tile t+2 -> buf0
        LOAD_A8(0, SBUF8); LOAD_B8(0, SBUF8);
        if (t + 2 < NT) STAGE_A8(t + 2, 0);
        PH_SYNC;
        __builtin_amdgcn_s_setprio(1); QMFMA8(0, 0); __builtin_amdgcn_s_setprio(0);
        __builtin_amdgcn_s_barrier();
        // PH5: q(0,1); stage B of tile t+2 -> buf0
        LOAD_B8(1, SBUF8);
        if (t + 2 < NT) STAGE_B8(t + 2, 0);
        PH_SYNC;
        __builtin_amdgcn_s_setprio(1); QMFMA8(0, 1); __builtin_amdgcn_s_setprio(0);
        __builtin_amdgcn_s_barrier();
        // PH6: q(1,0)
        LOAD_A8(1, SBUF8);
        PH_SYNC;
        __builtin_amdgcn_s_setprio(1); QMFMA8(1, 0); __builtin_amdgcn_s_setprio(0);
        __builtin_amdgcn_s_barrier();
        // PH7: q(1,1); boundary wait (tile t+2 loads, issued PH4-5)
        __builtin_amdgcn_s_setprio(1); QMFMA8(1, 1); __builtin_amdgcn_s_setprio(0);
        VM0_;
        __builtin_amdgcn_s_barrier();
    }

    // ---- epilogue ----
    int m0 = mt * 256;
#pragma unroll
    for (int mi = 0; mi < 8; mi++) {
#pragma unroll
        for (int nf = 0; nf < 4; nf++) {
            floatx4 v = acc[mi][nf];
            if (SWAP) {
                int rowL = m0 + wm * 128 + mi * 16 + lr;
                int col0 = n0 + wn * 64 + nf * 16 + lq * 4;
                if (col0 >= sLo) {
                    if (MODE == 5) {
                        bf16x4 pv;
#pragma unroll
                        for (int r = 0; r < 4; r++) pv[r] = (bf16)(v[r] + bias[col0 + r]);
                        *(bf16x4*)((bf16*)Cv + (long)rowL * 768 + col0) = pv;
                    } else if (MODE == 1) {
                        bf16* Cp = (bf16*)Cv;
                        bf16x4* ptr = (bf16x4*)(Cp + (long)rowL * ldc + col0);
                        bf16x4 old = *ptr;
                        bf16x4 pv;
#pragma unroll
                        for (int r = 0; r < 4; r++)
                            pv[r] = (bf16)((float)old[r] + v[r] + bias[col0 + r]);
                        *ptr = pv;
                    } else {
                        bf16x4 pv;
#pragma unroll
                        for (int r = 0; r < 4; r++) {
                            float x = v[r] + (bias ? bias[col0 + r] : 0.f);
                            if (relu) x = fmaxf(x, 0.f);
                            pv[r] = (bf16)x;
                        }
                        *(bf16x4*)((bf16*)Cv + (long)rowL * ldc + col0) = pv;
                    }
                }
            } else {
                // MODE 5 vt: lane holds col colL, rows row0..row0+3
                int row0 = m0 + wm * 128 + mi * 16 + lq * 4;
                int colL = n0 + wn * 64 + nf * 16 + lr;   // 768..1151
                if (colL >= sLo) {
                    float bv = bias[colL];
                    bf16x4 pv;
#pragma unroll
                    for (int r = 0; r < 4; r++) pv[r] = (bf16)(v[r] + bv);
                    int bidx = row0 >> 8, pos = row0 & 255, e = colL - 768;
                    *(bf16x4*)((bf16*)Cv2 + (long)bidx * (E * T) + (long)e * T + pos) = pv;
                }
            }
        }
    }
#undef STAGE_A8
#undef STAGE_B8
#undef LOAD_A8
#undef LOAD_B8
#undef QMFMA8
#undef PH_SYNC
#undef VM0_
}

template <int MODE>
__global__ __launch_bounds__(512, 2) void k_gemm8(
    const bf16* __restrict__ A, int lda,
    const bf16* __restrict__ Bf,
    const float* __restrict__ bias,
    void* __restrict__ Cv, void* __restrict__ Cv2, int ldc,
    int Mtiles, int Ntiles, int Ncols, int K,
    int relu)
{
    __shared__ __align__(16) char L[2 * SBUF8];   // 128 KB

    // XCD swizzle
    int nb = gridDim.x;
    int per = nb >> 3;
    int bphys = blockIdx.x;
    int bid = (bphys & 7) * per + (bphys >> 3);

    int nt = bid % Ntiles;
    int mt = bid / Ntiles;

    int n0 = nt * 256, sLo = 0;
    if (n0 + 256 > Ncols) { sLo = n0; n0 = Ncols - 256; }   // overlapped last tile

    if (MODE == 5 && n0 >= 768)
        gemm8_body<5, 0>(L, A, lda, Bf, bias, Cv, Cv2, ldc, n0, sLo, mt, Ncols, K, relu);
    else
        gemm8_body<MODE, 1>(L, A, lda, Bf, bias, Cv, Cv2, ldc, n0, sLo, mt, Ncols, K, relu);
}

// ---------------- legacy small GEMM (logits only): v8 W=4 path ----------------
template <int MODE, int W>
__device__ __forceinline__ void gemm_body(
    char* AsB,
    const bf16* __restrict__ A, int lda,
    const bf16* __restrict__ Bf,
    const float* __restrict__ bias,
    void* __restrict__ Cv, int ldc,
    int nt, int mt, int Nvalid, int K, int relu)
{
    constexpr int BM     = W * 32;
    constexpr int ABYTES = BM * 64;
    constexpr int SBUF   = ABYTES + 8192;

    int tid = threadIdx.x;
    int lane = tid & 63;
    int wid = tid >> 6;
    int wr = wid >> 1, wc = wid & 1;
    int lq = lane >> 4, lr = lane & 15;

    const bf16* Ab = A + (long)mt * BM * lda;

    int rp0 = wid * 8 + (lane >> 3);
    int s   = lane & 7;
    int sp  = s ^ (rp0 & 7);
    int rowA = 2 * rp0 + (sp >> 2);
    int kOff = (sp & 3) * 8;
    const bf16* srcA0 = Ab + (long)rowA * lda + kOff;
    const bf16* srcA1 = srcA0 + (long)(BM / 2) * lda;
    int dst0 = wid * 1024;
    int dst1 = W * 1024 + wid * 1024;

    int nks = K / 32;

    const bf16* srcB0 = Bf + ((long)(nt * 8 + wid * 2) * nks) * 512 + lane * 8;
    const bf16* srcB1 = Bf + ((long)(nt * 8 + wid * 2 + 1) * nks) * 512 + lane * 8;
    int dstB0 = ABYTES + (wid * 2) * 1024;
    int dstB1 = ABYTES + (wid * 2 + 1) * 1024;

    floatx4 acc[4][4];
#pragma unroll
    for (int i = 0; i < 4; i++)
#pragma unroll
        for (int j = 0; j < 4; j++) acc[i][j] = floatx4{0.f, 0.f, 0.f, 0.f};

    int afo = (wr * 32 + (lr >> 1)) * 128 +
              (((((lr & 1) << 2) | lq) ^ (lr >> 1)) << 4);
    int bfo = ABYTES + wc * 4096 + lane * 16;

    auto stage = [&](int ks, int bo) {
        long ka = (long)ks * 32;
        gload_lds16(srcA0 + ka, AsB + bo + dst0);
        gload_lds16(srcA1 + ka, AsB + bo + dst1);
        long kb = (long)ks * 512;
        gload_lds16(srcB0 + kb, AsB + bo + dstB0);
        gload_lds16(srcB1 + kb, AsB + bo + dstB1);
    };

    int o0 = 0, o1 = SBUF, o2 = 2 * SBUF;

    stage(0, o0);
    if (nks > 1) {
        stage(1, o1);
        asm volatile("s_waitcnt vmcnt(4)" ::: "memory");
    } else {
        asm volatile("s_waitcnt vmcnt(0)" ::: "memory");
    }
    __builtin_amdgcn_s_barrier();

    for (int ki = 0; ki < nks; ++ki) {
        if (ki + 2 < nks) stage(ki + 2, o2);
        __builtin_amdgcn_sched_barrier(0);

        bf16x8 bfr[4];
#pragma unroll
        for (int ni = 0; ni < 4; ni++)
            bfr[ni] = *(const bf16x8*)(AsB + o0 + bfo + ni * 1024);
        bf16x8 af[4];
#pragma unroll
        for (int mi = 0; mi < 4; mi++)
            af[mi] = *(const bf16x8*)(AsB + o0 + afo + mi * 1024);

        __builtin_amdgcn_s_setprio(1);
#pragma unroll
        for (int mi = 0; mi < 4; mi++)
#pragma unroll
            for (int ni = 0; ni < 4; ni++)
                acc[mi][ni] = __builtin_amdgcn_mfma_f32_16x16x32_bf16(
                    bfr[ni], af[mi], acc[mi][ni], 0, 0, 0);
        __builtin_amdgcn_s_setprio(0);

        if (ki + 1 < nks) {
            if (ki + 2 < nks)
                asm volatile("s_waitcnt vmcnt(4) lgkmcnt(0)" ::: "memory");
            else
                asm volatile("s_waitcnt vmcnt(0) lgkmcnt(0)" ::: "memory");
            __builtin_amdgcn_s_barrier();
        }
        int t = o0; o0 = o1; o1 = o2; o2 = t;
    }

    int m0 = mt * BM, n0 = nt * 128;
#pragma unroll
    for (int mi = 0; mi < 4; mi++) {
#pragma unroll
        for (int ni = 0; ni < 4; ni++) {
            floatx4 v = acc[mi][ni];
            int rowL = m0 + wr * 64 + mi * 16 + lr;
            int col0 = n0 + wc * 64 + ni * 16 + lq * 4;
            if (MODE == 4) {
                float* Cp = (float*)Cv;
#pragma unroll
                for (int r = 0; r < 4; r++)
                    if (col0 + r < Nvalid)
                        Cp[(long)rowL * ldc + col0 + r] = v[r] + bias[col0 + r];
            }
        }
    }
}

template <int MODE, int W>
__global__ __launch_bounds__(W * 64, 4) void k_gemm(
    const bf16* __restrict__ A, int lda,
    const bf16* __restrict__ Bf,
    const float* __restrict__ bias,
    void* __restrict__ Cv, void* __restrict__ Cv2, int ldc,
    int Mtiles, int Ntiles, int Nvalid, int K,
    int relu)
{
    __shared__ __align__(16) char AsB[3 * (W * 32 * 64 + 8192)];

    int nb = gridDim.x;
    int per = nb >> 3;
    int bphys = blockIdx.x;
    int bid = (bphys & 7) * per + (bphys >> 3);

    int nt = bid % Ntiles;
    int mt = bid / Ntiles;

    gemm_body<MODE, W>(AsB, A, lda, Bf, bias, Cv, ldc, nt, mt, Nvalid, K, relu);
}

// ---------------- fused causal attention (LDS-staged K/V) ----------------
__global__ __launch_bounds__(256) void k_attn(
    const bf16* __restrict__ qk, const bf16* __restrict__ vt,
    bf16* __restrict__ o)
{
    int nb = gridDim.x;
    int per = nb >> 3;
    int bphys = blockIdx.x;
    int bid = (bphys & 7) * per + (bphys >> 3);

    int qt = bid & 3; bid >>= 2;
    int h = bid % NH; int b = bid / NH;
    int tid = threadIdx.x;
    int lane = tid & 63;
    int w = tid >> 6;
    int lq = lane >> 4;     // 0..3
    int lr = lane & 15;

    __shared__ __align__(16) bf16 Ks[256 * 72];   // K rows padded; reused for P
    __shared__ __align__(16) bf16 Vs[64 * 264];   // V^T rows padded

    const bf16* qbase = qk + (long)(b * T + qt * 64 + w * 16) * 768 + h * 64;
    const bf16* kbase = qk + (long)(b * T) * 768 + 384 + h * 64;
    const bf16* vbase = vt + ((long)b * E + h * 64) * T;

#pragma unroll
    for (int i = 0; i < 8; i++) {
        int idx = i * 256 + tid;
        int row = idx >> 3, off = (idx & 7) * 8;
        *(bf16x8*)(&Ks[row * 72 + off]) = *(const bf16x8*)(kbase + (long)row * 768 + off);
    }
#pragma unroll
    for (int i = 0; i < 8; i++) {
        int idx = i * 256 + tid;
        int row = idx >> 5, off = (idx & 31) * 8;
        *(bf16x8*)(&Vs[row * 264 + off]) = *(const bf16x8*)(vbase + (long)row * 256 + off);
    }

    bf16x8 aq0 = *(const bf16x8*)(qbase + (long)lr * 768 + lq * 8);
    bf16x8 aq1 = *(const bf16x8*)(qbase + (long)lr * 768 + 32 + lq * 8);

    __syncthreads();

    const int ntmax = qt * 4 + 3;
    floatx4 zero = {0.f, 0.f, 0.f, 0.f};
    floatx4 s[16];
#pragma unroll
    for (int nt = 0; nt < 16; nt++) s[nt] = zero;

#pragma unroll
    for (int nt = 0; nt < 16; nt++) {
        if (nt <= ntmax) {
            const bf16* kp = &Ks[(nt * 16 + lr) * 72 + lq * 8];
            bf16x8 b0 = *(const bf16x8*)(kp);
            bf16x8 b1 = *(const bf16x8*)(kp + 32);
            s[nt] = __builtin_amdgcn_mfma_f32_16x16x32_bf16(aq0, b0, s[nt], 0, 0, 0);
            s[nt] = __builtin_amdgcn_mfma_f32_16x16x32_bf16(aq1, b1, s[nt], 0, 0, 0);
        }
    }

    int trow0 = qt * 64 + w * 16 + lq * 4;
    float m4[4] = {-3e38f, -3e38f, -3e38f, -3e38f};
#pragma unroll
    for (int nt = 0; nt < 16; nt++) {
        if (nt <= ntmax) {
            int tc = nt * 16 + lr;
#pragma unroll
            for (int r = 0; r < 4; r++) {
                float v = s[nt][r] * 0.125f;
                if (tc > trow0 + r) v = -3e38f;
                s[nt][r] = v;
                m4[r] = fmaxf(m4[r], v);
            }
        }
    }
#pragma unroll
    for (int r = 0; r < 4; r++) {
#pragma unroll
        for (int off = 1; off < 16; off <<= 1)
            m4[r] = fmaxf(m4[r], __shfl_xor(m4[r], off, 64));
    }

    float l4[4] = {0.f, 0.f, 0.f, 0.f};
#pragma unroll
    for (int nt = 0; nt < 16; nt++) {
        if (nt <= ntmax) {
#pragma unroll
            for (int r = 0; r < 4; r++) {
                float pv = __expf(s[nt][r] - m4[r]);
                l4[r] += pv;
                s[nt][r] = pv;
            }
        }
    }
#pragma unroll
    for (int r = 0; r < 4; r++) {
#pragma unroll
        for (int off = 1; off < 16; off <<= 1)
            l4[r] += __shfl_xor(l4[r], off, 64);
    }

    __syncthreads();   // Ks fully consumed -> reuse for P

    bf16* P = Ks + w * (16 * 264);
#pragma unroll
    for (int nt = 0; nt < 16; nt++) {
        if (nt <= ntmax) {
#pragma unroll
            for (int r = 0; r < 4; r++)
                P[(lq * 4 + r) * 264 + nt * 16 + lr] = (bf16)s[nt][r];
        }
    }

    floatx4 oacc[4];
#pragma unroll
    for (int nd = 0; nd < 4; nd++) oacc[nd] = zero;
    const int kkmax = 2 * (qt + 1);
#pragma unroll
    for (int kk = 0; kk < 8; kk++) {
        if (kk < kkmax) {
            bf16x8 ap = *(const bf16x8*)(&P[lr * 264 + kk * 32 + lq * 8]);
#pragma unroll
            for (int nd = 0; nd < 4; nd++) {
                bf16x8 bv = *(const bf16x8*)(&Vs[(nd * 16 + lr) * 264 + kk * 32 + lq * 8]);
                oacc[nd] = __builtin_amdgcn_mfma_f32_16x16x32_bf16(ap, bv, oacc[nd], 0, 0, 0);
            }
        }
    }

#pragma unroll
    for (int r = 0; r < 4; r++) {
        float inv = 1.0f / l4[r];
        long rowg = (long)b * T + trow0 + r;
#pragma unroll
        for (int nd = 0; nd < 4; nd++) {
            o[rowg * E + h * 64 + nd * 16 + lr] = (bf16)(oacc[nd][r] * inv);
        }
    }
}

// ---------------- layernorm: bf16 in -> bf16 out (wave per row) ----------------
__global__ void k_ln(const bf16* __restrict__ x, const float* __restrict__ g,
                     const float* __restrict__ b, bf16* __restrict__ h) {
    int row = blockIdx.x * 4 + (threadIdx.x >> 6);
    int lane = threadIdx.x & 63;
    const bf16* xr = x + (long)row * E;
    float v[6];
    float s = 0.f;
#pragma unroll
    for (int i = 0; i < 6; i++) { v[i] = (float)xr[lane + 64 * i]; s += v[i]; }
#pragma unroll
    for (int o = 1; o < 64; o <<= 1) s += __shfl_xor(s, o, 64);
    float mu = s * (1.0f / E);
    float q = 0.f;
#pragma unroll
    for (int i = 0; i < 6; i++) { float d = v[i] - mu; q += d * d; }
#pragma unroll
    for (int o = 1; o < 64; o <<= 1) q += __shfl_xor(q, o, 64);
    float rs = rsqrtf(q * (1.0f / E) + 1e-5f);
    bf16* hr = h + (long)row * E;
#pragma unroll
    for (int i = 0; i < 6; i++) {
        int c = lane + 64 * i;
        hr[c] = (bf16)((v[i] - mu) * rs * g[c] + b[c]);
    }
}

// ---------------- fragment-layout weight transpose ----------------
// W [L][K][N] (f32) -> Wf [L][NPAD/16][K/32][64][8] (bf16), cols>=N zero.
__global__ void k_transpose_frag(const float* __restrict__ W, bf16* __restrict__ Wf,
                                 int K, int N, int NPAD) {
    long idx = (long)blockIdx.x * 256 + threadIdx.x;
    long per = (long)NPAD * K;
    int l = (int)(idx / per);
    long r = idx - (long)l * per;
    int j = (int)(r & 7); r >>= 3;
    int lane = (int)(r & 63); r >>= 6;
    int nks = K / 32;
    int ks = (int)(r % nks);
    int c16 = (int)(r / nks);
    int col = c16 * 16 + (lane & 15);
    int k = ks * 32 + (lane >> 4) * 8 + j;
    Wf[idx] = (col < N) ? (bf16)W[((long)l * K + k) * N + col] : (bf16)0.0f;
}

// ---------------- fragment-layout fused QKV transpose: [L] cols 0..1151 ----------------
__global__ void k_transpose_qkv_frag(const float* __restrict__ Wq, const float* __restrict__ Wk,
                                     const float* __restrict__ Wv, bf16* __restrict__ Wf) {
    long idx = (long)blockIdx.x * 256 + threadIdx.x;
    long per = (long)1152 * E;
    int l = (int)(idx / per);
    long r = idx - (long)l * per;
    int j = (int)(r & 7); r >>= 3;
    int lane = (int)(r & 63); r >>= 6;
    int nks = E / 32;
    int ks = (int)(r % nks);
    int c16 = (int)(r / nks);
    int col = c16 * 16 + (lane & 15);
    int k = ks * 32 + (lane >> 4) * 8 + j;
    const float* src;
    int cc;
    if (col < 384)      { src = Wq; cc = col; }
    else if (col < 768) { src = Wk; cc = col - 384; }
    else                { src = Wv; cc = col - 768; }
    Wf[idx] = (bf16)src[((long)l * E + k) * E + cc];
}

// ---------------- fused QKV bias concat: [L][1152] f32 ----------------
__global__ void k_bias_qkv(const float* __restrict__ bq, const float* __restrict__ bk,
                           const float* __restrict__ bv, float* __restrict__ bqkv) {
    int idx = blockIdx.x * 256 + threadIdx.x;
    int l = idx / 1152;
    int j = idx - l * 1152;
    const float* src;
    int jj;
    if (j < 384)      { src = bq; jj = j; }
    else if (j < 768) { src = bk; jj = j - 384; }
    else              { src = bv; jj = j - 768; }
    bqkv[idx] = src[l * E + jj];
}

// ---------------- embedding + positional -> bf16 residual ----------------
__global__ void k_embed(const int* __restrict__ tokens, const float* __restrict__ pos,
                        const float* __restrict__ emb, bf16* __restrict__ x) {
    long idx = (long)blockIdx.x * 256 + threadIdx.x;
    int e = (int)(idx % E);
    long bt = idx / E;
    int t = (int)(bt % T);
    int tok = tokens[bt];
    x[idx] = (bf16)(emb[(long)tok * E + e] + pos[(long)t * E + e]);
}

// ---------------- launcher ----------------
extern "C" void kernel_launch(void* const* d_in, const int* in_sizes, int n_in,
                              void* d_out, int out_size, void* d_ws, size_t ws_size,
                              hipStream_t stream) {
    const int*   tokens = (const int*)d_in[0];
    const float* pos  = (const float*)d_in[1];
    const float* emb  = (const float*)d_in[2];
    const float* Wq   = (const float*)d_in[3];
    const float* bq   = (const float*)d_in[4];
    const float* Wk   = (const float*)d_in[5];
    const float* bk   = (const float*)d_in[6];
    const float* Wv   = (const float*)d_in[7];
    const float* bv   = (const float*)d_in[8];
    const float* Wo   = (const float*)d_in[9];
    const float* bo   = (const float*)d_in[10];
    const float* g1   = (const float*)d_in[11];
    const float* be1  = (const float*)d_in[12];
    const float* W1   = (const float*)d_in[13];
    const float* c1   = (const float*)d_in[14];
    const float* W2   = (const float*)d_in[15];
    const float* c2   = (const float*)d_in[16];
    const float* g2   = (const float*)d_in[17];
    const float* be2  = (const float*)d_in[18];
    const float* Wl   = (const float*)d_in[19];
    const float* bl   = (const float*)d_in[20];

    // ---- workspace layout (~173 MB peak, unchanged) ----
    char* p = (char*)d_ws;
    bf16* x  = (bf16*)p;   p += (long)MTOT * E * 2;          // residual (bf16)
    bf16* h  = (bf16*)p;   p += (long)MTOT * E * 2;          // LN out / o (alias)
    bf16* qk = (bf16*)p;   p += (long)MTOT * 768 * 2;        // fused Q|K
    bf16* vt = (bf16*)p;   p += (long)BB * E * T * 2;        // V^T per (seq,head)
    bf16* SP = (bf16*)p;   p += (long)CB * NH * T * T * 2;   // mid alias span
    bf16* WqkvF = (bf16*)p; p += (long)NL * 1152 * E * 2;    // fragment layouts
    bf16* WoF = (bf16*)p;  p += (long)NL * E * E * 2;
    bf16* W1F = (bf16*)p;  p += (long)NL * DFF * E * 2;
    bf16* W2F = (bf16*)p;  p += (long)NL * E * DFF * 2;
    bf16* WlF = (bf16*)p;  p += (long)128 * E * 2;
    float* bqkv = (float*)p; p += (long)NL * 1152 * 4;
    bf16* mid = qk;          // alias: qk+vt+SP = MTOT*DFF*2 exactly
    bf16* o   = h;
    (void)SP;

    // ---- setup (once per call) ----
    k_transpose_qkv_frag<<<(NL * 1152 * E) / 256, 256, 0, stream>>>(Wq, Wk, Wv, WqkvF);
    k_transpose_frag<<<(NL * E * E) / 256, 256, 0, stream>>>(Wo, WoF, E, E, E);
    k_transpose_frag<<<(NL * DFF * E) / 256, 256, 0, stream>>>(W1, W1F, E, DFF, DFF);
    k_transpose_frag<<<(NL * E * DFF) / 256, 256, 0, stream>>>(W2, W2F, DFF, E, E);
    k_transpose_frag<<<(128 * E) / 256, 256, 0, stream>>>(Wl, WlF, E, NV, 128);
    k_bias_qkv<<<(NL * 1152) / 256, 256, 0, stream>>>(bq, bk, bv, bqkv);

    // ---- embedding ----
    k_embed<<<(MTOT * E) / 256, 256, 0, stream>>>(tokens, pos, emb, x);

    for (int l = 0; l < NL; l++) {
        // LN1
        k_ln<<<MTOT / 4, 256, 0, stream>>>(x, g1 + l * E, be1 + l * E, h);
        // fused QKV: M=32768, N=1152 (5 overlapped 256-tiles), K=384
        k_gemm8<5><<<128 * 5, 512, 0, stream>>>(h, E, WqkvF + (long)l * 1152 * E,
                                                bqkv + l * 1152, qk, vt, 0,
                                                128, 5, 1152, E, 0);
        // fused causal attention
        k_attn<<<BB * NH * 4, 256, 0, stream>>>(qk, vt, o);
        // x += O @ Wo + bo: N=384 (2 overlapped tiles), K=384
        k_gemm8<1><<<128 * 2, 512, 0, stream>>>(o, E, WoF + (long)l * E * E,
                                                bo + l * E, x, nullptr, E,
                                                128, 2, 384, E, 0);
        // LN2
        k_ln<<<MTOT / 4, 256, 0, stream>>>(x, g2 + l * E, be2 + l * E, h);
        // mid = relu(h @ W1 + c1): N=1536 (6 exact tiles), K=384
        k_gemm8<0><<<128 * 6, 512, 0, stream>>>(h, E, W1F + (long)l * DFF * E,
                                                c1 + l * DFF, mid, nullptr, DFF,
                                                128, 6, 1536, E, 1);
        // x += mid @ W2 + c2: N=384 (2 overlapped tiles), K=1536
        k_gemm8<1><<<128 * 2, 512, 0, stream>>>(mid, DFF, W2F + (long)l * E * DFF,
                                                c2 + l * E, x, nullptr, E,
                                                128, 2, 384, DFF, 0);
    }

    // logits = x @ Wl + bl  (N=65 masked from 128), f32 out, legacy path
    k_gemm<4, 4><<<256 * 1, 256, 0, stream>>>(x, E, WlF,
                                              bl, d_out, nullptr, NV,
                                              256, 1, NV, E, 0);
}

// Round 10
// 1886.472 us; speedup vs baseline: 1.0411x; 1.0411x over previous
//
#include <hip/hip_runtime.h>
#include <hip/hip_bf16.h>
#include <stdint.h>

// ---------------- problem constants ----------------
constexpr int E   = 384;
constexpr int DFF = 1536;
constexpr int NH  = 6;
constexpr int HD  = 64;
constexpr int T   = 256;
constexpr int NL  = 6;
constexpr int NV  = 65;
constexpr int BB  = 128;
constexpr int MTOT = BB * T;           // 32768 rows
constexpr int CB  = 32;                // (kept for ws layout compatibility)

typedef __bf16 bf16;
typedef __attribute__((ext_vector_type(8))) __bf16 bf16x8;
typedef __attribute__((ext_vector_type(4))) __bf16 bf16x4;
typedef __attribute__((ext_vector_type(4))) float floatx4;

// direct global->LDS DMA, 16B per lane (dest = wave-uniform base + lane*16)
__device__ __forceinline__ void gload_lds16(const void* g, void* l) {
    __builtin_amdgcn_global_load_lds(
        (const __attribute__((address_space(1))) void*)g,
        (__attribute__((address_space(3))) void*)l, 16, 0, 0);
}

// ---------------- generic bf16 GEMM: C = A[M,K] @ W ----------------
// v11 = r7's v8 GEMM (best measured: FFN1 69us) + LN FOLDED INTO EPILOGUE.
// Ten schedule variants (r0-r9) all pinned MfmaUtil at 17-22% — with K=384
// (3 pipeline iters/block) the steady-state schedule is not the lever.
// So: bank algorithmic savings. LN(x)@W = rs*(x@(g.W)) - (mu*rs)*u + w
// with u_n = sum_c g_c W_cn, w_n = sum_c beta_c W_cn (precomputed); per-row
// (mu*rs, rs) from a tiny stats kernel. Kills all k_ln dispatches + the
// h round-trip (50MB/layer).
// Pipeline (unchanged, r7-verified): BK=32, triple-buffered A+B in LDS via
// global_load_lds, counted s_waitcnt vmcnt at barriers (never drain-0
// mid-loop); A source-side XOR swizzle (0 conflicts r1-r9); B linear c16
// groups, each B byte crosses L2 once.
// W=8: BM=256, 2 blocks/CU. W=4: BM=128 for small-N GEMMs (grid balance).
// MODE 0: bf16 out (+bias,+relu) | MODE 1: residual += | MODE 2: LN-folded
// bf16 out (+relu) | MODE 4: f32 out + N-mask | MODE 5: LN-folded QKV split
#define GBN 128

template <int MODE, int SWAP, int W>
__device__ __forceinline__ void gemm_body(
    char* AsB,
    const bf16* __restrict__ A, int lda,
    const bf16* __restrict__ Bf,
    const float* __restrict__ bias,
    void* __restrict__ Cv, void* __restrict__ Cv2, int ldc,
    int nt, int mt, int Nvalid, int K, int relu,
    const float2* __restrict__ st, const float* __restrict__ uvec)
{
    constexpr int BM     = W * 32;
    constexpr int ABYTES = BM * 64;          // A bytes per K-step buffer
    constexpr int SBUF   = ABYTES + 8192;    // + B bytes (128 cols x 32 k)

    int tid = threadIdx.x;
    int lane = tid & 63;
    int wid = tid >> 6;
    int wr = wid >> 1, wc = wid & 1;         // 64x64 out per wave
    int lq = lane >> 4, lr = lane & 15;

    const bf16* Ab = A + (long)mt * BM * lda;

    // ---- A staging map (DMA, 2 chunks/wave) ----
    int rp0 = wid * 8 + (lane >> 3);
    int s   = lane & 7;
    int sp  = s ^ (rp0 & 7);
    int rowA = 2 * rp0 + (sp >> 2);
    int kOff = (sp & 3) * 8;
    const bf16* srcA0 = Ab + (long)rowA * lda + kOff;
    const bf16* srcA1 = srcA0 + (long)(BM / 2) * lda;
    int dst0 = wid * 1024;
    int dst1 = W * 1024 + wid * 1024;

    int nks = K / 32;

    // ---- B staging map: c16 group g (0..7) -> ABYTES + g*1024 + lane*16 ----
    const bf16* srcB0;
    const bf16* srcB1 = nullptr;
    int dstB0, dstB1 = 0;
    if constexpr (W == 8) {
        srcB0 = Bf + ((long)(nt * 8 + wid) * nks) * 512 + lane * 8;
        dstB0 = ABYTES + wid * 1024;
    } else {
        srcB0 = Bf + ((long)(nt * 8 + wid * 2) * nks) * 512 + lane * 8;
        srcB1 = Bf + ((long)(nt * 8 + wid * 2 + 1) * nks) * 512 + lane * 8;
        dstB0 = ABYTES + (wid * 2) * 1024;
        dstB1 = ABYTES + (wid * 2 + 1) * 1024;
    }

    floatx4 acc[4][4];
#pragma unroll
    for (int i = 0; i < 4; i++)
#pragma unroll
        for (int j = 0; j < 4; j++) acc[i][j] = floatx4{0.f, 0.f, 0.f, 0.f};

    int afo = (wr * 32 + (lr >> 1)) * 128 +
              (((((lr & 1) << 2) | lq) ^ (lr >> 1)) << 4);
    int bfo = ABYTES + wc * 4096 + lane * 16;

    auto stage = [&](int ks, int bo) {
        long ka = (long)ks * 32;
        gload_lds16(srcA0 + ka, AsB + bo + dst0);
        gload_lds16(srcA1 + ka, AsB + bo + dst1);
        long kb = (long)ks * 512;
        gload_lds16(srcB0 + kb, AsB + bo + dstB0);
        if constexpr (W == 4)
            gload_lds16(srcB1 + kb, AsB + bo + dstB1);
    };

    int o0 = 0, o1 = SBUF, o2 = 2 * SBUF;

    // ---- prologue: stage tiles 0 and 1; wait tile0 (counted) ----
    stage(0, o0);
    if (nks > 1) {
        stage(1, o1);
        if constexpr (W == 8)
            asm volatile("s_waitcnt vmcnt(3)" ::: "memory");
        else
            asm volatile("s_waitcnt vmcnt(4)" ::: "memory");
    } else {
        asm volatile("s_waitcnt vmcnt(0)" ::: "memory");
    }
    __builtin_amdgcn_s_barrier();

    for (int ki = 0; ki < nks; ++ki) {
        // depth-2 prefetch into the third buffer (stays in flight across
        // this iter's barrier — counted wait below never drains it)
        if (ki + 2 < nks) stage(ki + 2, o2);
        __builtin_amdgcn_sched_barrier(0);

        bf16x8 bfr[4];
#pragma unroll
        for (int ni = 0; ni < 4; ni++)
            bfr[ni] = *(const bf16x8*)(AsB + o0 + bfo + ni * 1024);
        bf16x8 af[4];
#pragma unroll
        for (int mi = 0; mi < 4; mi++)
            af[mi] = *(const bf16x8*)(AsB + o0 + afo + mi * 1024);

        __builtin_amdgcn_s_setprio(1);
#pragma unroll
        for (int mi = 0; mi < 4; mi++)
#pragma unroll
            for (int ni = 0; ni < 4; ni++)
                acc[mi][ni] = SWAP
                    ? __builtin_amdgcn_mfma_f32_16x16x32_bf16(bfr[ni], af[mi], acc[mi][ni], 0, 0, 0)
                    : __builtin_amdgcn_mfma_f32_16x16x32_bf16(af[mi], bfr[ni], acc[mi][ni], 0, 0, 0);
        __builtin_amdgcn_s_setprio(0);

        if (ki + 1 < nks) {
            if (ki + 2 < nks) {
                if constexpr (W == 8)
                    asm volatile("s_waitcnt vmcnt(3) lgkmcnt(0)" ::: "memory");
                else
                    asm volatile("s_waitcnt vmcnt(4) lgkmcnt(0)" ::: "memory");
            } else {
                asm volatile("s_waitcnt vmcnt(0) lgkmcnt(0)" ::: "memory");
            }
            __builtin_amdgcn_s_barrier();
        }
        int t = o0; o0 = o1; o1 = o2; o2 = t;
    }

    int m0 = mt * BM, n0 = nt * GBN;
#pragma unroll
    for (int mi = 0; mi < 4; mi++) {
#pragma unroll
        for (int ni = 0; ni < 4; ni++) {
            floatx4 v = acc[mi][ni];
            if (SWAP) {
                // lane holds row rowL, cols col0..col0+3
                int rowL = m0 + wr * 64 + mi * 16 + lr;
                int col0 = n0 + wc * 64 + ni * 16 + lq * 4;
                if (MODE == 5) {
                    float2 s2 = st[rowL];          // (mu*rs, rs)
                    bf16x4 pv;
#pragma unroll
                    for (int r = 0; r < 4; r++)
                        pv[r] = (bf16)(s2.y * v[r] - s2.x * uvec[col0 + r] + bias[col0 + r]);
                    *(bf16x4*)((bf16*)Cv + (long)rowL * 768 + col0) = pv;
                } else if (MODE == 2) {
                    if (col0 < Nvalid) {
                        float2 s2 = st[rowL];
                        bf16x4 pv;
#pragma unroll
                        for (int r = 0; r < 4; r++) {
                            float x = s2.y * v[r] - s2.x * uvec[col0 + r] + bias[col0 + r];
                            if (relu) x = fmaxf(x, 0.f);
                            pv[r] = (bf16)x;
                        }
                        *(bf16x4*)((bf16*)Cv + (long)rowL * ldc + col0) = pv;
                    }
                } else if (MODE == 1) {
                    bf16* Cp = (bf16*)Cv;
                    bf16x4* ptr = (bf16x4*)(Cp + (long)rowL * ldc + col0);
                    bf16x4 old = *ptr;
                    bf16x4 pv;
#pragma unroll
                    for (int r = 0; r < 4; r++)
                        pv[r] = (bf16)((float)old[r] + v[r] + bias[col0 + r]);
                    *ptr = pv;
                } else if (MODE == 4) {
                    float* Cp = (float*)Cv;
#pragma unroll
                    for (int r = 0; r < 4; r++)
                        if (col0 + r < Nvalid)
                            Cp[(long)rowL * ldc + col0 + r] = v[r] + bias[col0 + r];
                } else {
                    if (col0 < Nvalid) {
                        bf16x4 pv;
#pragma unroll
                        for (int r = 0; r < 4; r++) {
                            float x = v[r] + (bias ? bias[col0 + r] : 0.f);
                            if (relu) x = fmaxf(x, 0.f);
                            pv[r] = (bf16)x;
                        }
                        *(bf16x4*)((bf16*)Cv + (long)rowL * ldc + col0) = pv;
                    }
                }
            } else {
                // MODE 5 vt blocks: lane holds col colL, rows row0..row0+3
                int row0 = m0 + wr * 64 + mi * 16 + lq * 4;
                int colL = n0 + wc * 64 + ni * 16 + lr;   // 768..1151
                float uu = uvec[colL];
                float cc = bias[colL];
                bf16x4 pv;
#pragma unroll
                for (int r = 0; r < 4; r++) {
                    float2 s2 = st[row0 + r];
                    pv[r] = (bf16)(s2.y * v[r] - s2.x * uu + cc);
                }
                int bidx = row0 >> 8, pos = row0 & 255, e = colL - 768;
                *(bf16x4*)((bf16*)Cv2 + (long)bidx * (E * T) + (long)e * T + pos) = pv;
            }
        }
    }
}

template <int MODE, int W>
__global__ __launch_bounds__(W * 64, 4) void k_gemm(
    const bf16* __restrict__ A, int lda,
    const bf16* __restrict__ Bf,
    const float* __restrict__ bias,
    void* __restrict__ Cv, void* __restrict__ Cv2, int ldc,
    int Mtiles, int Ntiles, int Nvalid, int K,
    int relu,
    const float2* __restrict__ st, const float* __restrict__ uvec)
{
    __shared__ __align__(16) char AsB[3 * (W * 32 * 64 + 8192)];

    // XCD swizzle: all N-tiles of an M-tile land on one XCD's L2.
    int nb = gridDim.x;
    int per = nb >> 3;
    int bphys = blockIdx.x;
    int bid = (bphys & 7) * per + (bphys >> 3);

    int nt = bid % Ntiles;
    int mt = bid / Ntiles;

    if (MODE == 5 && nt >= 6)
        gemm_body<5, 0, W>(AsB, A, lda, Bf, bias, Cv, Cv2, ldc, nt, mt, Nvalid, K, relu, st, uvec);
    else
        gemm_body<MODE, 1, W>(AsB, A, lda, Bf, bias, Cv, Cv2, ldc, nt, mt, Nvalid, K, relu, st, uvec);
}

// ---------------- fused causal attention (LDS-staged K/V) ----------------
__global__ __launch_bounds__(256) void k_attn(
    const bf16* __restrict__ qk, const bf16* __restrict__ vt,
    bf16* __restrict__ o)
{
    int nb = gridDim.x;
    int per = nb >> 3;
    int bphys = blockIdx.x;
    int bid = (bphys & 7) * per + (bphys >> 3);

    int qt = bid & 3; bid >>= 2;
    int h = bid % NH; int b = bid / NH;
    int tid = threadIdx.x;
    int lane = tid & 63;
    int w = tid >> 6;
    int lq = lane >> 4;     // 0..3
    int lr = lane & 15;

    __shared__ __align__(16) bf16 Ks[256 * 72];   // K rows padded; reused for P
    __shared__ __align__(16) bf16 Vs[64 * 264];   // V^T rows padded

    const bf16* qbase = qk + (long)(b * T + qt * 64 + w * 16) * 768 + h * 64;
    const bf16* kbase = qk + (long)(b * T) * 768 + 384 + h * 64;
    const bf16* vbase = vt + ((long)b * E + h * 64) * T;

#pragma unroll
    for (int i = 0; i < 8; i++) {
        int idx = i * 256 + tid;
        int row = idx >> 3, off = (idx & 7) * 8;
        *(bf16x8*)(&Ks[row * 72 + off]) = *(const bf16x8*)(kbase + (long)row * 768 + off);
    }
#pragma unroll
    for (int i = 0; i < 8; i++) {
        int idx = i * 256 + tid;
        int row = idx >> 5, off = (idx & 31) * 8;
        *(bf16x8*)(&Vs[row * 264 + off]) = *(const bf16x8*)(vbase + (long)row * 256 + off);
    }

    bf16x8 aq0 = *(const bf16x8*)(qbase + (long)lr * 768 + lq * 8);
    bf16x8 aq1 = *(const bf16x8*)(qbase + (long)lr * 768 + 32 + lq * 8);

    __syncthreads();

    const int ntmax = qt * 4 + 3;
    floatx4 zero = {0.f, 0.f, 0.f, 0.f};
    floatx4 s[16];
#pragma unroll
    for (int nt = 0; nt < 16; nt++) s[nt] = zero;

#pragma unroll
    for (int nt = 0; nt < 16; nt++) {
        if (nt <= ntmax) {
            const bf16* kp = &Ks[(nt * 16 + lr) * 72 + lq * 8];
            bf16x8 b0 = *(const bf16x8*)(kp);
            bf16x8 b1 = *(const bf16x8*)(kp + 32);
            s[nt] = __builtin_amdgcn_mfma_f32_16x16x32_bf16(aq0, b0, s[nt], 0, 0, 0);
            s[nt] = __builtin_amdgcn_mfma_f32_16x16x32_bf16(aq1, b1, s[nt], 0, 0, 0);
        }
    }

    int trow0 = qt * 64 + w * 16 + lq * 4;
    float m4[4] = {-3e38f, -3e38f, -3e38f, -3e38f};
#pragma unroll
    for (int nt = 0; nt < 16; nt++) {
        if (nt <= ntmax) {
            int tc = nt * 16 + lr;
#pragma unroll
            for (int r = 0; r < 4; r++) {
                float v = s[nt][r] * 0.125f;
                if (tc > trow0 + r) v = -3e38f;
                s[nt][r] = v;
                m4[r] = fmaxf(m4[r], v);
            }
        }
    }
#pragma unroll
    for (int r = 0; r < 4; r++) {
#pragma unroll
        for (int off = 1; off < 16; off <<= 1)
            m4[r] = fmaxf(m4[r], __shfl_xor(m4[r], off, 64));
    }

    float l4[4] = {0.f, 0.f, 0.f, 0.f};
#pragma unroll
    for (int nt = 0; nt < 16; nt++) {
        if (nt <= ntmax) {
#pragma unroll
            for (int r = 0; r < 4; r++) {
                float pv = __expf(s[nt][r] - m4[r]);
                l4[r] += pv;
                s[nt][r] = pv;
            }
        }
    }
#pragma unroll
    for (int r = 0; r < 4; r++) {
#pragma unroll
        for (int off = 1; off < 16; off <<= 1)
            l4[r] += __shfl_xor(l4[r], off, 64);
    }

    __syncthreads();   // Ks fully consumed -> reuse for P

    bf16* P = Ks + w * (16 * 264);
#pragma unroll
    for (int nt = 0; nt < 16; nt++) {
        if (nt <= ntmax) {
#pragma unroll
            for (int r = 0; r < 4; r++)
                P[(lq * 4 + r) * 264 + nt * 16 + lr] = (bf16)s[nt][r];
        }
    }

    floatx4 oacc[4];
#pragma unroll
    for (int nd = 0; nd < 4; nd++) oacc[nd] = zero;
    const int kkmax = 2 * (qt + 1);
#pragma unroll
    for (int kk = 0; kk < 8; kk++) {
        if (kk < kkmax) {
            bf16x8 ap = *(const bf16x8*)(&P[lr * 264 + kk * 32 + lq * 8]);
#pragma unroll
            for (int nd = 0; nd < 4; nd++) {
                bf16x8 bv = *(const bf16x8*)(&Vs[(nd * 16 + lr) * 264 + kk * 32 + lq * 8]);
                oacc[nd] = __builtin_amdgcn_mfma_f32_16x16x32_bf16(ap, bv, oacc[nd], 0, 0, 0);
            }
        }
    }

#pragma unroll
    for (int r = 0; r < 4; r++) {
        float inv = 1.0f / l4[r];
        long rowg = (long)b * T + trow0 + r;
#pragma unroll
        for (int nd = 0; nd < 4; nd++) {
            o[rowg * E + h * 64 + nd * 16 + lr] = (bf16)(oacc[nd][r] * inv);
        }
    }
}

// ---------------- row stats: (mu*rs, rs) per row of x ----------------
__global__ void k_stats(const bf16* __restrict__ x, float2* __restrict__ st) {
    int row = blockIdx.x * 4 + (threadIdx.x >> 6);
    int lane = threadIdx.x & 63;
    const bf16* xr = x + (long)row * E;
    float v[6];
    float s = 0.f;
#pragma unroll
    for (int i = 0; i < 6; i++) { v[i] = (float)xr[lane + 64 * i]; s += v[i]; }
#pragma unroll
    for (int o = 1; o < 64; o <<= 1) s += __shfl_xor(s, o, 64);
    float mu = s * (1.0f / E);
    float q = 0.f;
#pragma unroll
    for (int i = 0; i < 6; i++) { float d = v[i] - mu; q += d * d; }
#pragma unroll
    for (int o = 1; o < 64; o <<= 1) q += __shfl_xor(q, o, 64);
    float rs = rsqrtf(q * (1.0f / E) + 1e-5f);
    if (lane == 0) st[row] = make_float2(mu * rs, rs);
}

// ---------------- fragment-layout weight transpose (optional g-scale) ----------------
// W [L][K][N] (f32) -> Wf [L][NPAD/16][K/32][64][8] (bf16), cols>=N zero.
// If g != nullptr, W row c is pre-scaled by g[l*K+c] (LN gamma folding).
__global__ void k_transpose_frag(const float* __restrict__ W, const float* __restrict__ g,
                                 bf16* __restrict__ Wf, int K, int N, int NPAD) {
    long idx = (long)blockIdx.x * 256 + threadIdx.x;   // over NL*NPAD*K
    long per = (long)NPAD * K;
    int l = (int)(idx / per);
    long r = idx - (long)l * per;
    int j = (int)(r & 7); r >>= 3;
    int lane = (int)(r & 63); r >>= 6;
    int nks = K / 32;
    int ks = (int)(r % nks);
    int c16 = (int)(r / nks);
    int col = c16 * 16 + (lane & 15);
    int k = ks * 32 + (lane >> 4) * 8 + j;
    float sc = g ? g[(long)l * K + k] : 1.0f;
    Wf[idx] = (col < N) ? (bf16)(W[((long)l * K + k) * N + col] * sc) : (bf16)0.0f;
}

// ---------------- fused QKV transpose (g1-scaled): [L] cols 0..1151 ----------------
__global__ void k_transpose_qkv_frag(const float* __restrict__ Wq, const float* __restrict__ Wk,
                                     const float* __restrict__ Wv, const float* __restrict__ g1,
                                     bf16* __restrict__ Wf) {
    long idx = (long)blockIdx.x * 256 + threadIdx.x;   // over NL*1152*384
    long per = (long)1152 * E;
    int l = (int)(idx / per);
    long r = idx - (long)l * per;
    int j = (int)(r & 7); r >>= 3;
    int lane = (int)(r & 63); r >>= 6;
    int nks = E / 32;                                   // 12
    int ks = (int)(r % nks);
    int c16 = (int)(r / nks);
    int col = c16 * 16 + (lane & 15);                   // 0..1151
    int k = ks * 32 + (lane >> 4) * 8 + j;
    const float* src;
    int cc;
    if (col < 384)      { src = Wq; cc = col; }
    else if (col < 768) { src = Wk; cc = col - 384; }
    else                { src = Wv; cc = col - 768; }
    Wf[idx] = (bf16)(src[((long)l * E + k) * E + cc] * g1[(long)l * E + k]);
}

// ---------------- QKV column constants: u_n = sum g*W, cv_n = sum be*W + b ----------------
__global__ void k_colconst_qkv(const float* __restrict__ Wq, const float* __restrict__ Wk,
                               const float* __restrict__ Wv, const float* __restrict__ g,
                               const float* __restrict__ bb,
                               const float* __restrict__ bq, const float* __restrict__ bk,
                               const float* __restrict__ bv,
                               float* __restrict__ u, float* __restrict__ cv) {
    int idx = blockIdx.x * 256 + threadIdx.x;   // over NL*1152
    int l = idx / 1152, n = idx - l * 1152;
    const float* W; const float* bsrc; int cc;
    if (n < 384)      { W = Wq; bsrc = bq; cc = n; }
    else if (n < 768) { W = Wk; bsrc = bk; cc = n - 384; }
    else              { W = Wv; bsrc = bv; cc = n - 768; }
    float su = 0.f, sw = 0.f;
    for (int c = 0; c < E; c++) {
        float w = W[((long)l * E + c) * E + cc];
        su += g[(long)l * E + c] * w;
        sw += bb[(long)l * E + c] * w;
    }
    u[idx] = su;
    cv[idx] = sw + bsrc[(long)l * E + cc];
}

// ---------------- generic column constants (FFN1) ----------------
__global__ void k_colconst(const float* __restrict__ W, const float* __restrict__ g,
                           const float* __restrict__ bb, const float* __restrict__ bias,
                           float* __restrict__ u, float* __restrict__ cv, int K, int N) {
    int idx = blockIdx.x * 256 + threadIdx.x;   // over NL*N
    int l = idx / N, n = idx - l * N;
    float su = 0.f, sw = 0.f;
    for (int c = 0; c < K; c++) {
        float w = W[((long)l * K + c) * N + n];
        su += g[(long)l * K + c] * w;
        sw += bb[(long)l * K + c] * w;
    }
    u[idx] = su;
    cv[idx] = sw + bias[idx];
}

// ---------------- embedding + positional -> bf16 residual ----------------
__global__ void k_embed(const int* __restrict__ tokens, const float* __restrict__ pos,
                        const float* __restrict__ emb, bf16* __restrict__ x) {
    long idx = (long)blockIdx.x * 256 + threadIdx.x;
    int e = (int)(idx % E);
    long bt = idx / E;
    int t = (int)(bt % T);
    int tok = tokens[bt];
    x[idx] = (bf16)(emb[(long)tok * E + e] + pos[(long)t * E + e]);
}

// ---------------- launcher ----------------
extern "C" void kernel_launch(void* const* d_in, const int* in_sizes, int n_in,
                              void* d_out, int out_size, void* d_ws, size_t ws_size,
                              hipStream_t stream) {
    const int*   tokens = (const int*)d_in[0];
    const float* pos  = (const float*)d_in[1];
    const float* emb  = (const float*)d_in[2];
    const float* Wq   = (const float*)d_in[3];
    const float* bq   = (const float*)d_in[4];
    const float* Wk   = (const float*)d_in[5];
    const float* bk   = (const float*)d_in[6];
    const float* Wv   = (const float*)d_in[7];
    const float* bv   = (const float*)d_in[8];
    const float* Wo   = (const float*)d_in[9];
    const float* bo   = (const float*)d_in[10];
    const float* g1   = (const float*)d_in[11];
    const float* be1  = (const float*)d_in[12];
    const float* W1   = (const float*)d_in[13];
    const float* c1   = (const float*)d_in[14];
    const float* W2   = (const float*)d_in[15];
    const float* c2   = (const float*)d_in[16];
    const float* g2   = (const float*)d_in[17];
    const float* be2  = (const float*)d_in[18];
    const float* Wl   = (const float*)d_in[19];
    const float* bl   = (const float*)d_in[20];

    // ---- workspace layout (~174 MB peak) ----
    char* p = (char*)d_ws;
    bf16* x  = (bf16*)p;   p += (long)MTOT * E * 2;          // residual (bf16)
    bf16* h  = (bf16*)p;   p += (long)MTOT * E * 2;          // o (attn out)
    bf16* qk = (bf16*)p;   p += (long)MTOT * 768 * 2;        // fused Q|K
    bf16* vt = (bf16*)p;   p += (long)BB * E * T * 2;        // V^T per (seq,head)
    bf16* SP = (bf16*)p;   p += (long)CB * NH * T * T * 2;   // mid alias span
    bf16* WqkvF = (bf16*)p; p += (long)NL * 1152 * E * 2;    // fragment layouts
    bf16* WoF = (bf16*)p;  p += (long)NL * E * E * 2;
    bf16* W1F = (bf16*)p;  p += (long)NL * DFF * E * 2;
    bf16* W2F = (bf16*)p;  p += (long)NL * E * DFF * 2;
    bf16* WlF = (bf16*)p;  p += (long)128 * E * 2;
    float2* st1 = (float2*)p; p += (long)MTOT * 8;           // LN1 stats (mu*rs, rs)
    float2* st2 = (float2*)p; p += (long)MTOT * 8;           // LN2 stats
    float* uq  = (float*)p; p += (long)NL * 1152 * 4;        // QKV colsum(g.W)
    float* cq  = (float*)p; p += (long)NL * 1152 * 4;        // QKV colsum(be.W)+b
    float* u1  = (float*)p; p += (long)NL * DFF * 4;         // FFN1 colsum
    float* c1v = (float*)p; p += (long)NL * DFF * 4;
    bf16* mid = qk;          // alias: qk+vt+SP = MTOT*DFF*2 exactly
    bf16* o   = h;
    (void)SP;

    // ---- setup (once per call) ----
    k_transpose_qkv_frag<<<(NL * 1152 * E) / 256, 256, 0, stream>>>(Wq, Wk, Wv, g1, WqkvF);
    k_transpose_frag<<<(NL * E * E) / 256, 256, 0, stream>>>(Wo, nullptr, WoF, E, E, E);
    k_transpose_frag<<<(NL * DFF * E) / 256, 256, 0, stream>>>(W1, g2, W1F, E, DFF, DFF);
    k_transpose_frag<<<(NL * E * DFF) / 256, 256, 0, stream>>>(W2, nullptr, W2F, DFF, E, E);
    k_transpose_frag<<<(128 * E) / 256, 256, 0, stream>>>(Wl, nullptr, WlF, E, NV, 128);
    k_colconst_qkv<<<(NL * 1152) / 256, 256, 0, stream>>>(Wq, Wk, Wv, g1, be1,
                                                          bq, bk, bv, uq, cq);
    k_colconst<<<(NL * DFF) / 256, 256, 0, stream>>>(W1, g2, be2, c1, u1, c1v, E, DFF);

    // ---- embedding ----
    k_embed<<<(MTOT * E) / 256, 256, 0, stream>>>(tokens, pos, emb, x);

    for (int l = 0; l < NL; l++) {
        // LN1 stats only (LN folded into QKV epilogue)
        k_stats<<<MTOT / 4, 256, 0, stream>>>(x, st1);
        // fused QKV on x: M=32768, N=1152, K=384
        k_gemm<5, 8><<<128 * 9, 512, 0, stream>>>(x, E, WqkvF + (long)l * 1152 * E,
                                                  cq + l * 1152, qk, vt, 0,
                                                  128, 9, 1152, E, 0,
                                                  st1, uq + l * 1152);
        // fused causal attention
        k_attn<<<BB * NH * 4, 256, 0, stream>>>(qk, vt, o);
        // x += O @ Wo + bo
        k_gemm<1, 4><<<256 * 3, 256, 0, stream>>>(o, E, WoF + (long)l * E * E,
                                                  bo + l * E, x, nullptr, E,
                                                  256, 3, E, E, 0, nullptr, nullptr);
        // LN2 stats only
        k_stats<<<MTOT / 4, 256, 0, stream>>>(x, st2);
        // mid = relu(LN2(x) @ W1 + c1), LN folded
        k_gemm<2, 8><<<128 * 12, 512, 0, stream>>>(x, E, W1F + (long)l * DFF * E,
                                                   c1v + l * DFF, mid, nullptr, DFF,
                                                   128, 12, DFF, E, 1,
                                                   st2, u1 + l * DFF);
        // x += mid @ W2 + c2
        k_gemm<1, 4><<<256 * 3, 256, 0, stream>>>(mid, DFF, W2F + (long)l * E * DFF,
                                                  c2 + l * E, x, nullptr, E,
                                                  256, 3, E, DFF, 0, nullptr, nullptr);
    }

    // logits = x @ Wl + bl  (N=65 masked from 128), f32 out
    k_gemm<4, 4><<<256 * 1, 256, 0, stream>>>(x, E, WlF,
                                              bl, d_out, nullptr, NV,
                                              256, 1, NV, E, 0, nullptr, nullptr);
}

// Round 11
// 1804.942 us; speedup vs baseline: 1.0881x; 1.0452x over previous
//
#include <hip/hip_runtime.h>
#include <hip/hip_bf16.h>
#include <stdint.h>

// ---------------- problem constants ----------------
constexpr int E   = 384;
constexpr int DFF = 1536;
constexpr int NH  = 6;
constexpr int HD  = 64;
constexpr int T   = 256;
constexpr int NL  = 6;
constexpr int NV  = 65;
constexpr int BB  = 128;
constexpr int MTOT = BB * T;           // 32768 rows
constexpr int CB  = 32;                // (kept for ws layout compatibility)

typedef __bf16 bf16;
typedef __attribute__((ext_vector_type(8))) __bf16 bf16x8;
typedef __attribute__((ext_vector_type(4))) __bf16 bf16x4;
typedef __attribute__((ext_vector_type(4))) float floatx4;

// direct global->LDS DMA, 16B per lane (dest = wave-uniform base + lane*16)
__device__ __forceinline__ void gload_lds16(const void* g, void* l) {
    __builtin_amdgcn_global_load_lds(
        (const __attribute__((address_space(1))) void*)g,
        (__attribute__((address_space(3))) void*)l, 16, 0, 0);
}

// ---------------- generic bf16 GEMM: C = A[M,K] @ W ----------------
// v12 = v11 (r7 GEMM + LN folded into epilogue) with the r10 regression
// fixed: the two colconst setup kernels were serial-loop latency-bound
// (110us each, top of the profile); now parallel reductions (~10us).
// LN fold: LN(x)@W = rs*(x@(g.W)) - (mu*rs)*u + w; u,w precomputed per
// layer; per-row (mu*rs, rs) from k_stats (8B/row).
// Pipeline (r7-verified): BK=32, triple-buffered A+B in LDS via
// global_load_lds, counted s_waitcnt vmcnt at barriers; A source-side XOR
// swizzle (0 conflicts r1-r10); B linear c16 groups.
// MODE 0: bf16 out (+bias,+relu) | MODE 1: residual += | MODE 2: LN-folded
// bf16 out (+relu) | MODE 4: f32 out + N-mask | MODE 5: LN-folded QKV split
#define GBN 128

template <int MODE, int SWAP, int W>
__device__ __forceinline__ void gemm_body(
    char* AsB,
    const bf16* __restrict__ A, int lda,
    const bf16* __restrict__ Bf,
    const float* __restrict__ bias,
    void* __restrict__ Cv, void* __restrict__ Cv2, int ldc,
    int nt, int mt, int Nvalid, int K, int relu,
    const float2* __restrict__ st, const float* __restrict__ uvec)
{
    constexpr int BM     = W * 32;
    constexpr int ABYTES = BM * 64;          // A bytes per K-step buffer
    constexpr int SBUF   = ABYTES + 8192;    // + B bytes (128 cols x 32 k)

    int tid = threadIdx.x;
    int lane = tid & 63;
    int wid = tid >> 6;
    int wr = wid >> 1, wc = wid & 1;         // 64x64 out per wave
    int lq = lane >> 4, lr = lane & 15;

    const bf16* Ab = A + (long)mt * BM * lda;

    // ---- A staging map (DMA, 2 chunks/wave) ----
    int rp0 = wid * 8 + (lane >> 3);
    int s   = lane & 7;
    int sp  = s ^ (rp0 & 7);
    int rowA = 2 * rp0 + (sp >> 2);
    int kOff = (sp & 3) * 8;
    const bf16* srcA0 = Ab + (long)rowA * lda + kOff;
    const bf16* srcA1 = srcA0 + (long)(BM / 2) * lda;
    int dst0 = wid * 1024;
    int dst1 = W * 1024 + wid * 1024;

    int nks = K / 32;

    // ---- B staging map: c16 group g (0..7) -> ABYTES + g*1024 + lane*16 ----
    const bf16* srcB0;
    const bf16* srcB1 = nullptr;
    int dstB0, dstB1 = 0;
    if constexpr (W == 8) {
        srcB0 = Bf + ((long)(nt * 8 + wid) * nks) * 512 + lane * 8;
        dstB0 = ABYTES + wid * 1024;
    } else {
        srcB0 = Bf + ((long)(nt * 8 + wid * 2) * nks) * 512 + lane * 8;
        srcB1 = Bf + ((long)(nt * 8 + wid * 2 + 1) * nks) * 512 + lane * 8;
        dstB0 = ABYTES + (wid * 2) * 1024;
        dstB1 = ABYTES + (wid * 2 + 1) * 1024;
    }

    floatx4 acc[4][4];
#pragma unroll
    for (int i = 0; i < 4; i++)
#pragma unroll
        for (int j = 0; j < 4; j++) acc[i][j] = floatx4{0.f, 0.f, 0.f, 0.f};

    int afo = (wr * 32 + (lr >> 1)) * 128 +
              (((((lr & 1) << 2) | lq) ^ (lr >> 1)) << 4);
    int bfo = ABYTES + wc * 4096 + lane * 16;

    auto stage = [&](int ks, int bo) {
        long ka = (long)ks * 32;
        gload_lds16(srcA0 + ka, AsB + bo + dst0);
        gload_lds16(srcA1 + ka, AsB + bo + dst1);
        long kb = (long)ks * 512;
        gload_lds16(srcB0 + kb, AsB + bo + dstB0);
        if constexpr (W == 4)
            gload_lds16(srcB1 + kb, AsB + bo + dstB1);
    };

    int o0 = 0, o1 = SBUF, o2 = 2 * SBUF;

    // ---- prologue: stage tiles 0 and 1; wait tile0 (counted) ----
    stage(0, o0);
    if (nks > 1) {
        stage(1, o1);
        if constexpr (W == 8)
            asm volatile("s_waitcnt vmcnt(3)" ::: "memory");
        else
            asm volatile("s_waitcnt vmcnt(4)" ::: "memory");
    } else {
        asm volatile("s_waitcnt vmcnt(0)" ::: "memory");
    }
    __builtin_amdgcn_s_barrier();

    for (int ki = 0; ki < nks; ++ki) {
        // depth-2 prefetch into the third buffer (stays in flight across
        // this iter's barrier — counted wait below never drains it)
        if (ki + 2 < nks) stage(ki + 2, o2);
        __builtin_amdgcn_sched_barrier(0);

        bf16x8 bfr[4];
#pragma unroll
        for (int ni = 0; ni < 4; ni++)
            bfr[ni] = *(const bf16x8*)(AsB + o0 + bfo + ni * 1024);
        bf16x8 af[4];
#pragma unroll
        for (int mi = 0; mi < 4; mi++)
            af[mi] = *(const bf16x8*)(AsB + o0 + afo + mi * 1024);

        __builtin_amdgcn_s_setprio(1);
#pragma unroll
        for (int mi = 0; mi < 4; mi++)
#pragma unroll
            for (int ni = 0; ni < 4; ni++)
                acc[mi][ni] = SWAP
                    ? __builtin_amdgcn_mfma_f32_16x16x32_bf16(bfr[ni], af[mi], acc[mi][ni], 0, 0, 0)
                    : __builtin_amdgcn_mfma_f32_16x16x32_bf16(af[mi], bfr[ni], acc[mi][ni], 0, 0, 0);
        __builtin_amdgcn_s_setprio(0);

        if (ki + 1 < nks) {
            if (ki + 2 < nks) {
                if constexpr (W == 8)
                    asm volatile("s_waitcnt vmcnt(3) lgkmcnt(0)" ::: "memory");
                else
                    asm volatile("s_waitcnt vmcnt(4) lgkmcnt(0)" ::: "memory");
            } else {
                asm volatile("s_waitcnt vmcnt(0) lgkmcnt(0)" ::: "memory");
            }
            __builtin_amdgcn_s_barrier();
        }
        int t = o0; o0 = o1; o1 = o2; o2 = t;
    }

    int m0 = mt * BM, n0 = nt * GBN;
#pragma unroll
    for (int mi = 0; mi < 4; mi++) {
#pragma unroll
        for (int ni = 0; ni < 4; ni++) {
            floatx4 v = acc[mi][ni];
            if (SWAP) {
                // lane holds row rowL, cols col0..col0+3
                int rowL = m0 + wr * 64 + mi * 16 + lr;
                int col0 = n0 + wc * 64 + ni * 16 + lq * 4;
                if (MODE == 5) {
                    float2 s2 = st[rowL];          // (mu*rs, rs)
                    bf16x4 pv;
#pragma unroll
                    for (int r = 0; r < 4; r++)
                        pv[r] = (bf16)(s2.y * v[r] - s2.x * uvec[col0 + r] + bias[col0 + r]);
                    *(bf16x4*)((bf16*)Cv + (long)rowL * 768 + col0) = pv;
                } else if (MODE == 2) {
                    if (col0 < Nvalid) {
                        float2 s2 = st[rowL];
                        bf16x4 pv;
#pragma unroll
                        for (int r = 0; r < 4; r++) {
                            float x = s2.y * v[r] - s2.x * uvec[col0 + r] + bias[col0 + r];
                            if (relu) x = fmaxf(x, 0.f);
                            pv[r] = (bf16)x;
                        }
                        *(bf16x4*)((bf16*)Cv + (long)rowL * ldc + col0) = pv;
                    }
                } else if (MODE == 1) {
                    bf16* Cp = (bf16*)Cv;
                    bf16x4* ptr = (bf16x4*)(Cp + (long)rowL * ldc + col0);
                    bf16x4 old = *ptr;
                    bf16x4 pv;
#pragma unroll
                    for (int r = 0; r < 4; r++)
                        pv[r] = (bf16)((float)old[r] + v[r] + bias[col0 + r]);
                    *ptr = pv;
                } else if (MODE == 4) {
                    float* Cp = (float*)Cv;
#pragma unroll
                    for (int r = 0; r < 4; r++)
                        if (col0 + r < Nvalid)
                            Cp[(long)rowL * ldc + col0 + r] = v[r] + bias[col0 + r];
                } else {
                    if (col0 < Nvalid) {
                        bf16x4 pv;
#pragma unroll
                        for (int r = 0; r < 4; r++) {
                            float x = v[r] + (bias ? bias[col0 + r] : 0.f);
                            if (relu) x = fmaxf(x, 0.f);
                            pv[r] = (bf16)x;
                        }
                        *(bf16x4*)((bf16*)Cv + (long)rowL * ldc + col0) = pv;
                    }
                }
            } else {
                // MODE 5 vt blocks: lane holds col colL, rows row0..row0+3
                int row0 = m0 + wr * 64 + mi * 16 + lq * 4;
                int colL = n0 + wc * 64 + ni * 16 + lr;   // 768..1151
                float uu = uvec[colL];
                float cc = bias[colL];
                bf16x4 pv;
#pragma unroll
                for (int r = 0; r < 4; r++) {
                    float2 s2 = st[row0 + r];
                    pv[r] = (bf16)(s2.y * v[r] - s2.x * uu + cc);
                }
                int bidx = row0 >> 8, pos = row0 & 255, e = colL - 768;
                *(bf16x4*)((bf16*)Cv2 + (long)bidx * (E * T) + (long)e * T + pos) = pv;
            }
        }
    }
}

template <int MODE, int W>
__global__ __launch_bounds__(W * 64, 4) void k_gemm(
    const bf16* __restrict__ A, int lda,
    const bf16* __restrict__ Bf,
    const float* __restrict__ bias,
    void* __restrict__ Cv, void* __restrict__ Cv2, int ldc,
    int Mtiles, int Ntiles, int Nvalid, int K,
    int relu,
    const float2* __restrict__ st, const float* __restrict__ uvec)
{
    __shared__ __align__(16) char AsB[3 * (W * 32 * 64 + 8192)];

    // XCD swizzle: all N-tiles of an M-tile land on one XCD's L2.
    int nb = gridDim.x;
    int per = nb >> 3;
    int bphys = blockIdx.x;
    int bid = (bphys & 7) * per + (bphys >> 3);

    int nt = bid % Ntiles;
    int mt = bid / Ntiles;

    if (MODE == 5 && nt >= 6)
        gemm_body<5, 0, W>(AsB, A, lda, Bf, bias, Cv, Cv2, ldc, nt, mt, Nvalid, K, relu, st, uvec);
    else
        gemm_body<MODE, 1, W>(AsB, A, lda, Bf, bias, Cv, Cv2, ldc, nt, mt, Nvalid, K, relu, st, uvec);
}

// ---------------- fused causal attention (LDS-staged K/V) ----------------
__global__ __launch_bounds__(256) void k_attn(
    const bf16* __restrict__ qk, const bf16* __restrict__ vt,
    bf16* __restrict__ o)
{
    int nb = gridDim.x;
    int per = nb >> 3;
    int bphys = blockIdx.x;
    int bid = (bphys & 7) * per + (bphys >> 3);

    int qt = bid & 3; bid >>= 2;
    int h = bid % NH; int b = bid / NH;
    int tid = threadIdx.x;
    int lane = tid & 63;
    int w = tid >> 6;
    int lq = lane >> 4;     // 0..3
    int lr = lane & 15;

    __shared__ __align__(16) bf16 Ks[256 * 72];   // K rows padded; reused for P
    __shared__ __align__(16) bf16 Vs[64 * 264];   // V^T rows padded

    const bf16* qbase = qk + (long)(b * T + qt * 64 + w * 16) * 768 + h * 64;
    const bf16* kbase = qk + (long)(b * T) * 768 + 384 + h * 64;
    const bf16* vbase = vt + ((long)b * E + h * 64) * T;

#pragma unroll
    for (int i = 0; i < 8; i++) {
        int idx = i * 256 + tid;
        int row = idx >> 3, off = (idx & 7) * 8;
        *(bf16x8*)(&Ks[row * 72 + off]) = *(const bf16x8*)(kbase + (long)row * 768 + off);
    }
#pragma unroll
    for (int i = 0; i < 8; i++) {
        int idx = i * 256 + tid;
        int row = idx >> 5, off = (idx & 31) * 8;
        *(bf16x8*)(&Vs[row * 264 + off]) = *(const bf16x8*)(vbase + (long)row * 256 + off);
    }

    bf16x8 aq0 = *(const bf16x8*)(qbase + (long)lr * 768 + lq * 8);
    bf16x8 aq1 = *(const bf16x8*)(qbase + (long)lr * 768 + 32 + lq * 8);

    __syncthreads();

    const int ntmax = qt * 4 + 3;
    floatx4 zero = {0.f, 0.f, 0.f, 0.f};
    floatx4 s[16];
#pragma unroll
    for (int nt = 0; nt < 16; nt++) s[nt] = zero;

#pragma unroll
    for (int nt = 0; nt < 16; nt++) {
        if (nt <= ntmax) {
            const bf16* kp = &Ks[(nt * 16 + lr) * 72 + lq * 8];
            bf16x8 b0 = *(const bf16x8*)(kp);
            bf16x8 b1 = *(const bf16x8*)(kp + 32);
            s[nt] = __builtin_amdgcn_mfma_f32_16x16x32_bf16(aq0, b0, s[nt], 0, 0, 0);
            s[nt] = __builtin_amdgcn_mfma_f32_16x16x32_bf16(aq1, b1, s[nt], 0, 0, 0);
        }
    }

    int trow0 = qt * 64 + w * 16 + lq * 4;
    float m4[4] = {-3e38f, -3e38f, -3e38f, -3e38f};
#pragma unroll
    for (int nt = 0; nt < 16; nt++) {
        if (nt <= ntmax) {
            int tc = nt * 16 + lr;
#pragma unroll
            for (int r = 0; r < 4; r++) {
                float v = s[nt][r] * 0.125f;
                if (tc > trow0 + r) v = -3e38f;
                s[nt][r] = v;
                m4[r] = fmaxf(m4[r], v);
            }
        }
    }
#pragma unroll
    for (int r = 0; r < 4; r++) {
#pragma unroll
        for (int off = 1; off < 16; off <<= 1)
            m4[r] = fmaxf(m4[r], __shfl_xor(m4[r], off, 64));
    }

    float l4[4] = {0.f, 0.f, 0.f, 0.f};
#pragma unroll
    for (int nt = 0; nt < 16; nt++) {
        if (nt <= ntmax) {
#pragma unroll
            for (int r = 0; r < 4; r++) {
                float pv = __expf(s[nt][r] - m4[r]);
                l4[r] += pv;
                s[nt][r] = pv;
            }
        }
    }
#pragma unroll
    for (int r = 0; r < 4; r++) {
#pragma unroll
        for (int off = 1; off < 16; off <<= 1)
            l4[r] += __shfl_xor(l4[r], off, 64);
    }

    __syncthreads();   // Ks fully consumed -> reuse for P

    bf16* P = Ks + w * (16 * 264);
#pragma unroll
    for (int nt = 0; nt < 16; nt++) {
        if (nt <= ntmax) {
#pragma unroll
            for (int r = 0; r < 4; r++)
                P[(lq * 4 + r) * 264 + nt * 16 + lr] = (bf16)s[nt][r];
        }
    }

    floatx4 oacc[4];
#pragma unroll
    for (int nd = 0; nd < 4; nd++) oacc[nd] = zero;
    const int kkmax = 2 * (qt + 1);
#pragma unroll
    for (int kk = 0; kk < 8; kk++) {
        if (kk < kkmax) {
            bf16x8 ap = *(const bf16x8*)(&P[lr * 264 + kk * 32 + lq * 8]);
#pragma unroll
            for (int nd = 0; nd < 4; nd++) {
                bf16x8 bv = *(const bf16x8*)(&Vs[(nd * 16 + lr) * 264 + kk * 32 + lq * 8]);
                oacc[nd] = __builtin_amdgcn_mfma_f32_16x16x32_bf16(ap, bv, oacc[nd], 0, 0, 0);
            }
        }
    }

#pragma unroll
    for (int r = 0; r < 4; r++) {
        float inv = 1.0f / l4[r];
        long rowg = (long)b * T + trow0 + r;
#pragma unroll
        for (int nd = 0; nd < 4; nd++) {
            o[rowg * E + h * 64 + nd * 16 + lr] = (bf16)(oacc[nd][r] * inv);
        }
    }
}

// ---------------- row stats: (mu*rs, rs) per row of x ----------------
__global__ void k_stats(const bf16* __restrict__ x, float2* __restrict__ st) {
    int row = blockIdx.x * 4 + (threadIdx.x >> 6);
    int lane = threadIdx.x & 63;
    const bf16* xr = x + (long)row * E;
    float v[6];
    float s = 0.f;
#pragma unroll
    for (int i = 0; i < 6; i++) { v[i] = (float)xr[lane + 64 * i]; s += v[i]; }
#pragma unroll
    for (int o = 1; o < 64; o <<= 1) s += __shfl_xor(s, o, 64);
    float mu = s * (1.0f / E);
    float q = 0.f;
#pragma unroll
    for (int i = 0; i < 6; i++) { float d = v[i] - mu; q += d * d; }
#pragma unroll
    for (int o = 1; o < 64; o <<= 1) q += __shfl_xor(q, o, 64);
    float rs = rsqrtf(q * (1.0f / E) + 1e-5f);
    if (lane == 0) st[row] = make_float2(mu * rs, rs);
}

// ---------------- fragment-layout weight transpose (optional g-scale) ----------------
// W [L][K][N] (f32) -> Wf [L][NPAD/16][K/32][64][8] (bf16), cols>=N zero.
// If g != nullptr, W row c is pre-scaled by g[l*K+c] (LN gamma folding).
__global__ void k_transpose_frag(const float* __restrict__ W, const float* __restrict__ g,
                                 bf16* __restrict__ Wf, int K, int N, int NPAD) {
    long idx = (long)blockIdx.x * 256 + threadIdx.x;   // over NL*NPAD*K
    long per = (long)NPAD * K;
    int l = (int)(idx / per);
    long r = idx - (long)l * per;
    int j = (int)(r & 7); r >>= 3;
    int lane = (int)(r & 63); r >>= 6;
    int nks = K / 32;
    int ks = (int)(r % nks);
    int c16 = (int)(r / nks);
    int col = c16 * 16 + (lane & 15);
    int k = ks * 32 + (lane >> 4) * 8 + j;
    float sc = g ? g[(long)l * K + k] : 1.0f;
    Wf[idx] = (col < N) ? (bf16)(W[((long)l * K + k) * N + col] * sc) : (bf16)0.0f;
}

// ---------------- fused QKV transpose (g1-scaled): [L] cols 0..1151 ----------------
__global__ void k_transpose_qkv_frag(const float* __restrict__ Wq, const float* __restrict__ Wk,
                                     const float* __restrict__ Wv, const float* __restrict__ g1,
                                     bf16* __restrict__ Wf) {
    long idx = (long)blockIdx.x * 256 + threadIdx.x;   // over NL*1152*384
    long per = (long)1152 * E;
    int l = (int)(idx / per);
    long r = idx - (long)l * per;
    int j = (int)(r & 7); r >>= 3;
    int lane = (int)(r & 63); r >>= 6;
    int nks = E / 32;                                   // 12
    int ks = (int)(r % nks);
    int c16 = (int)(r / nks);
    int col = c16 * 16 + (lane & 15);                   // 0..1151
    int k = ks * 32 + (lane >> 4) * 8 + j;
    const float* src;
    int cc;
    if (col < 384)      { src = Wq; cc = col; }
    else if (col < 768) { src = Wk; cc = col - 384; }
    else                { src = Wv; cc = col - 768; }
    Wf[idx] = (bf16)(src[((long)l * E + k) * E + cc] * g1[(long)l * E + k]);
}

// ---------------- QKV column constants (PARALLEL): u, cv ----------------
// block: 256 thr = 4 c-parts x 64 cols; grid = NL * 1152/64 = 108 blocks
__global__ void k_colconst_qkv(const float* __restrict__ Wq, const float* __restrict__ Wk,
                               const float* __restrict__ Wv, const float* __restrict__ g,
                               const float* __restrict__ bb,
                               const float* __restrict__ bq, const float* __restrict__ bk,
                               const float* __restrict__ bv,
                               float* __restrict__ u, float* __restrict__ cv) {
    __shared__ float su_s[4][64], sw_s[4][64];
    int nb = 1152 / 64;
    int l  = blockIdx.x / nb;
    int n  = (blockIdx.x % nb) * 64 + (threadIdx.x & 63);
    int cp = threadIdx.x >> 6;     // 0..3
    const float* W; const float* bsrc; int cc;
    if (n < 384)      { W = Wq; bsrc = bq; cc = n; }
    else if (n < 768) { W = Wk; bsrc = bk; cc = n - 384; }
    else              { W = Wv; bsrc = bv; cc = n - 768; }
    float su = 0.f, sw = 0.f;
    for (int c = cp; c < E; c += 4) {
        float w = W[((long)l * E + c) * E + cc];
        su += g[(long)l * E + c] * w;
        sw += bb[(long)l * E + c] * w;
    }
    su_s[cp][threadIdx.x & 63] = su;
    sw_s[cp][threadIdx.x & 63] = sw;
    __syncthreads();
    if (cp == 0) {
        int nl = threadIdx.x & 63;
        float a = su_s[0][nl] + su_s[1][nl] + su_s[2][nl] + su_s[3][nl];
        float b = sw_s[0][nl] + sw_s[1][nl] + sw_s[2][nl] + sw_s[3][nl];
        u[(long)l * 1152 + n]  = a;
        cv[(long)l * 1152 + n] = b + bsrc[(long)l * E + cc];
    }
}

// ---------------- generic column constants (PARALLEL, FFN1) ----------------
// block: 256 thr = 4 c-parts x 64 cols; grid = NL * N/64
__global__ void k_colconst(const float* __restrict__ W, const float* __restrict__ g,
                           const float* __restrict__ bb, const float* __restrict__ bias,
                           float* __restrict__ u, float* __restrict__ cv, int K, int N) {
    __shared__ float su_s[4][64], sw_s[4][64];
    int nb = N / 64;
    int l  = blockIdx.x / nb;
    int n  = (blockIdx.x % nb) * 64 + (threadIdx.x & 63);
    int cp = threadIdx.x >> 6;     // 0..3
    float su = 0.f, sw = 0.f;
    for (int c = cp; c < K; c += 4) {
        float w = W[((long)l * K + c) * N + n];
        su += g[(long)l * K + c] * w;
        sw += bb[(long)l * K + c] * w;
    }
    su_s[cp][threadIdx.x & 63] = su;
    sw_s[cp][threadIdx.x & 63] = sw;
    __syncthreads();
    if (cp == 0) {
        int nl = threadIdx.x & 63;
        float a = su_s[0][nl] + su_s[1][nl] + su_s[2][nl] + su_s[3][nl];
        float b = sw_s[0][nl] + sw_s[1][nl] + sw_s[2][nl] + sw_s[3][nl];
        u[(long)l * N + n]  = a;
        cv[(long)l * N + n] = b + bias[(long)l * N + n];
    }
}

// ---------------- embedding + positional -> bf16 residual ----------------
__global__ void k_embed(const int* __restrict__ tokens, const float* __restrict__ pos,
                        const float* __restrict__ emb, bf16* __restrict__ x) {
    long idx = (long)blockIdx.x * 256 + threadIdx.x;
    int e = (int)(idx % E);
    long bt = idx / E;
    int t = (int)(bt % T);
    int tok = tokens[bt];
    x[idx] = (bf16)(emb[(long)tok * E + e] + pos[(long)t * E + e]);
}

// ---------------- launcher ----------------
extern "C" void kernel_launch(void* const* d_in, const int* in_sizes, int n_in,
                              void* d_out, int out_size, void* d_ws, size_t ws_size,
                              hipStream_t stream) {
    const int*   tokens = (const int*)d_in[0];
    const float* pos  = (const float*)d_in[1];
    const float* emb  = (const float*)d_in[2];
    const float* Wq   = (const float*)d_in[3];
    const float* bq   = (const float*)d_in[4];
    const float* Wk   = (const float*)d_in[5];
    const float* bk   = (const float*)d_in[6];
    const float* Wv   = (const float*)d_in[7];
    const float* bv   = (const float*)d_in[8];
    const float* Wo   = (const float*)d_in[9];
    const float* bo   = (const float*)d_in[10];
    const float* g1   = (const float*)d_in[11];
    const float* be1  = (const float*)d_in[12];
    const float* W1   = (const float*)d_in[13];
    const float* c1   = (const float*)d_in[14];
    const float* W2   = (const float*)d_in[15];
    const float* c2   = (const float*)d_in[16];
    const float* g2   = (const float*)d_in[17];
    const float* be2  = (const float*)d_in[18];
    const float* Wl   = (const float*)d_in[19];
    const float* bl   = (const float*)d_in[20];

    // ---- workspace layout (~174 MB peak) ----
    char* p = (char*)d_ws;
    bf16* x  = (bf16*)p;   p += (long)MTOT * E * 2;          // residual (bf16)
    bf16* h  = (bf16*)p;   p += (long)MTOT * E * 2;          // o (attn out)
    bf16* qk = (bf16*)p;   p += (long)MTOT * 768 * 2;        // fused Q|K
    bf16* vt = (bf16*)p;   p += (long)BB * E * T * 2;        // V^T per (seq,head)
    bf16* SP = (bf16*)p;   p += (long)CB * NH * T * T * 2;   // mid alias span
    bf16* WqkvF = (bf16*)p; p += (long)NL * 1152 * E * 2;    // fragment layouts
    bf16* WoF = (bf16*)p;  p += (long)NL * E * E * 2;
    bf16* W1F = (bf16*)p;  p += (long)NL * DFF * E * 2;
    bf16* W2F = (bf16*)p;  p += (long)NL * E * DFF * 2;
    bf16* WlF = (bf16*)p;  p += (long)128 * E * 2;
    float2* st1 = (float2*)p; p += (long)MTOT * 8;           // LN1 stats (mu*rs, rs)
    float2* st2 = (float2*)p; p += (long)MTOT * 8;           // LN2 stats
    float* uq  = (float*)p; p += (long)NL * 1152 * 4;        // QKV colsum(g.W)
    float* cq  = (float*)p; p += (long)NL * 1152 * 4;        // QKV colsum(be.W)+b
    float* u1  = (float*)p; p += (long)NL * DFF * 4;         // FFN1 colsum
    float* c1v = (float*)p; p += (long)NL * DFF * 4;
    bf16* mid = qk;          // alias: qk+vt+SP = MTOT*DFF*2 exactly
    bf16* o   = h;
    (void)SP;

    // ---- setup (once per call) ----
    k_transpose_qkv_frag<<<(NL * 1152 * E) / 256, 256, 0, stream>>>(Wq, Wk, Wv, g1, WqkvF);
    k_transpose_frag<<<(NL * E * E) / 256, 256, 0, stream>>>(Wo, nullptr, WoF, E, E, E);
    k_transpose_frag<<<(NL * DFF * E) / 256, 256, 0, stream>>>(W1, g2, W1F, E, DFF, DFF);
    k_transpose_frag<<<(NL * E * DFF) / 256, 256, 0, stream>>>(W2, nullptr, W2F, DFF, E, E);
    k_transpose_frag<<<(128 * E) / 256, 256, 0, stream>>>(Wl, nullptr, WlF, E, NV, 128);
    k_colconst_qkv<<<NL * (1152 / 64), 256, 0, stream>>>(Wq, Wk, Wv, g1, be1,
                                                         bq, bk, bv, uq, cq);
    k_colconst<<<NL * (DFF / 64), 256, 0, stream>>>(W1, g2, be2, c1, u1, c1v, E, DFF);

    // ---- embedding ----
    k_embed<<<(MTOT * E) / 256, 256, 0, stream>>>(tokens, pos, emb, x);

    for (int l = 0; l < NL; l++) {
        // LN1 stats only (LN folded into QKV epilogue)
        k_stats<<<MTOT / 4, 256, 0, stream>>>(x, st1);
        // fused QKV on x: M=32768, N=1152, K=384
        k_gemm<5, 8><<<128 * 9, 512, 0, stream>>>(x, E, WqkvF + (long)l * 1152 * E,
                                                  cq + l * 1152, qk, vt, 0,
                                                  128, 9, 1152, E, 0,
                                                  st1, uq + l * 1152);
        // fused causal attention
        k_attn<<<BB * NH * 4, 256, 0, stream>>>(qk, vt, o);
        // x += O @ Wo + bo
        k_gemm<1, 4><<<256 * 3, 256, 0, stream>>>(o, E, WoF + (long)l * E * E,
                                                  bo + l * E, x, nullptr, E,
                                                  256, 3, E, E, 0, nullptr, nullptr);
        // LN2 stats only
        k_stats<<<MTOT / 4, 256, 0, stream>>>(x, st2);
        // mid = relu(LN2(x) @ W1 + c1), LN folded
        k_gemm<2, 8><<<128 * 12, 512, 0, stream>>>(x, E, W1F + (long)l * DFF * E,
                                                   c1v + l * DFF, mid, nullptr, DFF,
                                                   128, 12, DFF, E, 1,
                                                   st2, u1 + l * DFF);
        // x += mid @ W2 + c2
        k_gemm<1, 4><<<256 * 3, 256, 0, stream>>>(mid, DFF, W2F + (long)l * E * DFF,
                                                  c2 + l * E, x, nullptr, E,
                                                  256, 3, E, DFF, 0, nullptr, nullptr);
    }

    // logits = x @ Wl + bl  (N=65 masked from 128), f32 out
    k_gemm<4, 4><<<256 * 1, 256, 0, stream>>>(x, E, WlF,
                                              bl, d_out, nullptr, NV,
                                              256, 1, NV, E, 0, nullptr, nullptr);
}

// Round 12
// 1788.999 us; speedup vs baseline: 1.0978x; 1.0089x over previous
//
#include <hip/hip_runtime.h>
#include <hip/hip_bf16.h>
#include <stdint.h>

// ---------------- problem constants ----------------
constexpr int E   = 384;
constexpr int DFF = 1536;
constexpr int NH  = 6;
constexpr int HD  = 64;
constexpr int T   = 256;
constexpr int NL  = 6;
constexpr int NV  = 65;
constexpr int BB  = 128;
constexpr int MTOT = BB * T;           // 32768 rows
constexpr int CB  = 32;                // (kept for ws layout compatibility)

typedef __bf16 bf16;
typedef __attribute__((ext_vector_type(8))) __bf16 bf16x8;
typedef __attribute__((ext_vector_type(4))) __bf16 bf16x4;
typedef __attribute__((ext_vector_type(4))) float floatx4;

// direct global->LDS DMA, 16B per lane (dest = wave-uniform base + lane*16)
__device__ __forceinline__ void gload_lds16(const void* g, void* l) {
    __builtin_amdgcn_global_load_lds(
        (const __attribute__((address_space(1))) void*)g,
        (__attribute__((address_space(3))) void*)l, 16, 0, 0);
}

// ---------------- generic bf16 GEMM: C = A[M,K] @ W ----------------
// v13 = r7's v8 GEMM restored verbatim (best measured total: 1701us; the
// r10/r11 LN-fold experiment measured NET NEGATIVE and is reverted).
// Changes vs r7 (both grid-shape only):
//  * QKV runs the W=4 path: grid 2304 = 3 EXACT rounds of 768 concurrent
//    blocks (3/CU at 48KB LDS). W=8 ran 1152 blocks = 2.25 rounds quantized
//    to 3 (last round 25% full) -> measured 77.7us vs ~58us of work.
//  * k_ln vectorized (bf16x8, G13).
// Pipeline (r7-verified): BK=32, triple-buffered A+B in LDS via
// global_load_lds, counted s_waitcnt vmcnt at barriers (never drain-0
// mid-loop); A source-side XOR swizzle (0 conflicts r1-r11); B linear c16
// groups (each B byte crosses L2 once).
// MODE 0: bf16 out (+bias,+relu,N-mask) | MODE 1: bf16 residual +=
// MODE 4: f32 out + N-mask | MODE 5: fused QKV (nt<6 qk | nt>=6 vt)
#define GBN 128

template <int MODE, int SWAP, int W>
__device__ __forceinline__ void gemm_body(
    char* AsB,
    const bf16* __restrict__ A, int lda,
    const bf16* __restrict__ Bf,
    const float* __restrict__ bias,
    void* __restrict__ Cv, void* __restrict__ Cv2, int ldc,
    int nt, int mt, int Nvalid, int K, int relu)
{
    constexpr int BM     = W * 32;
    constexpr int ABYTES = BM * 64;          // A bytes per K-step buffer
    constexpr int SBUF   = ABYTES + 8192;    // + B bytes (128 cols x 32 k)

    int tid = threadIdx.x;
    int lane = tid & 63;
    int wid = tid >> 6;
    int wr = wid >> 1, wc = wid & 1;         // 64x64 out per wave
    int lq = lane >> 4, lr = lane & 15;

    const bf16* Ab = A + (long)mt * BM * lda;

    // ---- A staging map (DMA, 2 chunks/wave) ----
    int rp0 = wid * 8 + (lane >> 3);
    int s   = lane & 7;
    int sp  = s ^ (rp0 & 7);
    int rowA = 2 * rp0 + (sp >> 2);
    int kOff = (sp & 3) * 8;
    const bf16* srcA0 = Ab + (long)rowA * lda + kOff;
    const bf16* srcA1 = srcA0 + (long)(BM / 2) * lda;
    int dst0 = wid * 1024;
    int dst1 = W * 1024 + wid * 1024;

    int nks = K / 32;

    // ---- B staging map: c16 group g (0..7) -> ABYTES + g*1024 + lane*16 ----
    const bf16* srcB0;
    const bf16* srcB1 = nullptr;
    int dstB0, dstB1 = 0;
    if constexpr (W == 8) {
        srcB0 = Bf + ((long)(nt * 8 + wid) * nks) * 512 + lane * 8;
        dstB0 = ABYTES + wid * 1024;
    } else {
        srcB0 = Bf + ((long)(nt * 8 + wid * 2) * nks) * 512 + lane * 8;
        srcB1 = Bf + ((long)(nt * 8 + wid * 2 + 1) * nks) * 512 + lane * 8;
        dstB0 = ABYTES + (wid * 2) * 1024;
        dstB1 = ABYTES + (wid * 2 + 1) * 1024;
    }

    floatx4 acc[4][4];
#pragma unroll
    for (int i = 0; i < 4; i++)
#pragma unroll
        for (int j = 0; j < 4; j++) acc[i][j] = floatx4{0.f, 0.f, 0.f, 0.f};

    int afo = (wr * 32 + (lr >> 1)) * 128 +
              (((((lr & 1) << 2) | lq) ^ (lr >> 1)) << 4);
    int bfo = ABYTES + wc * 4096 + lane * 16;

    auto stage = [&](int ks, int bo) {
        long ka = (long)ks * 32;
        gload_lds16(srcA0 + ka, AsB + bo + dst0);
        gload_lds16(srcA1 + ka, AsB + bo + dst1);
        long kb = (long)ks * 512;
        gload_lds16(srcB0 + kb, AsB + bo + dstB0);
        if constexpr (W == 4)
            gload_lds16(srcB1 + kb, AsB + bo + dstB1);
    };

    int o0 = 0, o1 = SBUF, o2 = 2 * SBUF;

    // ---- prologue: stage tiles 0 and 1; wait tile0 (counted) ----
    stage(0, o0);
    if (nks > 1) {
        stage(1, o1);
        if constexpr (W == 8)
            asm volatile("s_waitcnt vmcnt(3)" ::: "memory");
        else
            asm volatile("s_waitcnt vmcnt(4)" ::: "memory");
    } else {
        asm volatile("s_waitcnt vmcnt(0)" ::: "memory");
    }
    __builtin_amdgcn_s_barrier();

    for (int ki = 0; ki < nks; ++ki) {
        // depth-2 prefetch into the third buffer (stays in flight across
        // this iter's barrier — counted wait below never drains it)
        if (ki + 2 < nks) stage(ki + 2, o2);
        __builtin_amdgcn_sched_barrier(0);

        bf16x8 bfr[4];
#pragma unroll
        for (int ni = 0; ni < 4; ni++)
            bfr[ni] = *(const bf16x8*)(AsB + o0 + bfo + ni * 1024);
        bf16x8 af[4];
#pragma unroll
        for (int mi = 0; mi < 4; mi++)
            af[mi] = *(const bf16x8*)(AsB + o0 + afo + mi * 1024);

        __builtin_amdgcn_s_setprio(1);
#pragma unroll
        for (int mi = 0; mi < 4; mi++)
#pragma unroll
            for (int ni = 0; ni < 4; ni++)
                acc[mi][ni] = SWAP
                    ? __builtin_amdgcn_mfma_f32_16x16x32_bf16(bfr[ni], af[mi], acc[mi][ni], 0, 0, 0)
                    : __builtin_amdgcn_mfma_f32_16x16x32_bf16(af[mi], bfr[ni], acc[mi][ni], 0, 0, 0);
        __builtin_amdgcn_s_setprio(0);

        if (ki + 1 < nks) {
            if (ki + 2 < nks) {
                if constexpr (W == 8)
                    asm volatile("s_waitcnt vmcnt(3) lgkmcnt(0)" ::: "memory");
                else
                    asm volatile("s_waitcnt vmcnt(4) lgkmcnt(0)" ::: "memory");
            } else {
                asm volatile("s_waitcnt vmcnt(0) lgkmcnt(0)" ::: "memory");
            }
            __builtin_amdgcn_s_barrier();
        }
        int t = o0; o0 = o1; o1 = o2; o2 = t;
    }

    int m0 = mt * BM, n0 = nt * GBN;
#pragma unroll
    for (int mi = 0; mi < 4; mi++) {
#pragma unroll
        for (int ni = 0; ni < 4; ni++) {
            floatx4 v = acc[mi][ni];
            if (SWAP) {
                // lane holds row rowL, cols col0..col0+3
                int rowL = m0 + wr * 64 + mi * 16 + lr;
                int col0 = n0 + wc * 64 + ni * 16 + lq * 4;
                if (MODE == 5) {
                    bf16x4 pv;
#pragma unroll
                    for (int r = 0; r < 4; r++) pv[r] = (bf16)(v[r] + bias[col0 + r]);
                    *(bf16x4*)((bf16*)Cv + (long)rowL * 768 + col0) = pv;
                } else if (MODE == 1) {
                    bf16* Cp = (bf16*)Cv;
                    bf16x4* ptr = (bf16x4*)(Cp + (long)rowL * ldc + col0);
                    bf16x4 old = *ptr;
                    bf16x4 pv;
#pragma unroll
                    for (int r = 0; r < 4; r++)
                        pv[r] = (bf16)((float)old[r] + v[r] + bias[col0 + r]);
                    *ptr = pv;
                } else if (MODE == 4) {
                    float* Cp = (float*)Cv;
#pragma unroll
                    for (int r = 0; r < 4; r++)
                        if (col0 + r < Nvalid)
                            Cp[(long)rowL * ldc + col0 + r] = v[r] + bias[col0 + r];
                } else {
                    if (col0 < Nvalid) {
                        bf16x4 pv;
#pragma unroll
                        for (int r = 0; r < 4; r++) {
                            float x = v[r] + (bias ? bias[col0 + r] : 0.f);
                            if (relu) x = fmaxf(x, 0.f);
                            pv[r] = (bf16)x;
                        }
                        *(bf16x4*)((bf16*)Cv + (long)rowL * ldc + col0) = pv;
                    }
                }
            } else {
                // MODE 5 vt blocks: lane holds col colL, rows row0..row0+3
                int row0 = m0 + wr * 64 + mi * 16 + lq * 4;
                int colL = n0 + wc * 64 + ni * 16 + lr;   // 768..1151
                float bv = bias[colL];
                bf16x4 pv;
#pragma unroll
                for (int r = 0; r < 4; r++) pv[r] = (bf16)(v[r] + bv);
                int bidx = row0 >> 8, pos = row0 & 255, e = colL - 768;
                *(bf16x4*)((bf16*)Cv2 + (long)bidx * (E * T) + (long)e * T + pos) = pv;
            }
        }
    }
}

template <int MODE, int W>
__global__ __launch_bounds__(W * 64, 4) void k_gemm(
    const bf16* __restrict__ A, int lda,
    const bf16* __restrict__ Bf,
    const float* __restrict__ bias,
    void* __restrict__ Cv, void* __restrict__ Cv2, int ldc,
    int Mtiles, int Ntiles, int Nvalid, int K,
    int relu)
{
    __shared__ __align__(16) char AsB[3 * (W * 32 * 64 + 8192)];

    // XCD swizzle: all N-tiles of an M-tile land on one XCD's L2.
    int nb = gridDim.x;
    int per = nb >> 3;
    int bphys = blockIdx.x;
    int bid = (bphys & 7) * per + (bphys >> 3);

    int nt = bid % Ntiles;
    int mt = bid / Ntiles;

    if (MODE == 5 && nt >= 6)
        gemm_body<5, 0, W>(AsB, A, lda, Bf, bias, Cv, Cv2, ldc, nt, mt, Nvalid, K, relu);
    else
        gemm_body<MODE, 1, W>(AsB, A, lda, Bf, bias, Cv, Cv2, ldc, nt, mt, Nvalid, K, relu);
}

// ---------------- fused causal attention (LDS-staged K/V) ----------------
__global__ __launch_bounds__(256) void k_attn(
    const bf16* __restrict__ qk, const bf16* __restrict__ vt,
    bf16* __restrict__ o)
{
    int nb = gridDim.x;
    int per = nb >> 3;
    int bphys = blockIdx.x;
    int bid = (bphys & 7) * per + (bphys >> 3);

    int qt = bid & 3; bid >>= 2;
    int h = bid % NH; int b = bid / NH;
    int tid = threadIdx.x;
    int lane = tid & 63;
    int w = tid >> 6;
    int lq = lane >> 4;     // 0..3
    int lr = lane & 15;

    __shared__ __align__(16) bf16 Ks[256 * 72];   // K rows padded; reused for P
    __shared__ __align__(16) bf16 Vs[64 * 264];   // V^T rows padded

    const bf16* qbase = qk + (long)(b * T + qt * 64 + w * 16) * 768 + h * 64;
    const bf16* kbase = qk + (long)(b * T) * 768 + 384 + h * 64;
    const bf16* vbase = vt + ((long)b * E + h * 64) * T;

#pragma unroll
    for (int i = 0; i < 8; i++) {
        int idx = i * 256 + tid;
        int row = idx >> 3, off = (idx & 7) * 8;
        *(bf16x8*)(&Ks[row * 72 + off]) = *(const bf16x8*)(kbase + (long)row * 768 + off);
    }
#pragma unroll
    for (int i = 0; i < 8; i++) {
        int idx = i * 256 + tid;
        int row = idx >> 5, off = (idx & 31) * 8;
        *(bf16x8*)(&Vs[row * 264 + off]) = *(const bf16x8*)(vbase + (long)row * 256 + off);
    }

    bf16x8 aq0 = *(const bf16x8*)(qbase + (long)lr * 768 + lq * 8);
    bf16x8 aq1 = *(const bf16x8*)(qbase + (long)lr * 768 + 32 + lq * 8);

    __syncthreads();

    const int ntmax = qt * 4 + 3;
    floatx4 zero = {0.f, 0.f, 0.f, 0.f};
    floatx4 s[16];
#pragma unroll
    for (int nt = 0; nt < 16; nt++) s[nt] = zero;

#pragma unroll
    for (int nt = 0; nt < 16; nt++) {
        if (nt <= ntmax) {
            const bf16* kp = &Ks[(nt * 16 + lr) * 72 + lq * 8];
            bf16x8 b0 = *(const bf16x8*)(kp);
            bf16x8 b1 = *(const bf16x8*)(kp + 32);
            s[nt] = __builtin_amdgcn_mfma_f32_16x16x32_bf16(aq0, b0, s[nt], 0, 0, 0);
            s[nt] = __builtin_amdgcn_mfma_f32_16x16x32_bf16(aq1, b1, s[nt], 0, 0, 0);
        }
    }

    int trow0 = qt * 64 + w * 16 + lq * 4;
    float m4[4] = {-3e38f, -3e38f, -3e38f, -3e38f};
#pragma unroll
    for (int nt = 0; nt < 16; nt++) {
        if (nt <= ntmax) {
            int tc = nt * 16 + lr;
#pragma unroll
            for (int r = 0; r < 4; r++) {
                float v = s[nt][r] * 0.125f;
                if (tc > trow0 + r) v = -3e38f;
                s[nt][r] = v;
                m4[r] = fmaxf(m4[r], v);
            }
        }
    }
#pragma unroll
    for (int r = 0; r < 4; r++) {
#pragma unroll
        for (int off = 1; off < 16; off <<= 1)
            m4[r] = fmaxf(m4[r], __shfl_xor(m4[r], off, 64));
    }

    float l4[4] = {0.f, 0.f, 0.f, 0.f};
#pragma unroll
    for (int nt = 0; nt < 16; nt++) {
        if (nt <= ntmax) {
#pragma unroll
            for (int r = 0; r < 4; r++) {
                float pv = __expf(s[nt][r] - m4[r]);
                l4[r] += pv;
                s[nt][r] = pv;
            }
        }
    }
#pragma unroll
    for (int r = 0; r < 4; r++) {
#pragma unroll
        for (int off = 1; off < 16; off <<= 1)
            l4[r] += __shfl_xor(l4[r], off, 64);
    }

    __syncthreads();   // Ks fully consumed -> reuse for P

    bf16* P = Ks + w * (16 * 264);
#pragma unroll
    for (int nt = 0; nt < 16; nt++) {
        if (nt <= ntmax) {
#pragma unroll
            for (int r = 0; r < 4; r++)
                P[(lq * 4 + r) * 264 + nt * 16 + lr] = (bf16)s[nt][r];
        }
    }

    floatx4 oacc[4];
#pragma unroll
    for (int nd = 0; nd < 4; nd++) oacc[nd] = zero;
    const int kkmax = 2 * (qt + 1);
#pragma unroll
    for (int kk = 0; kk < 8; kk++) {
        if (kk < kkmax) {
            bf16x8 ap = *(const bf16x8*)(&P[lr * 264 + kk * 32 + lq * 8]);
#pragma unroll
            for (int nd = 0; nd < 4; nd++) {
                bf16x8 bv = *(const bf16x8*)(&Vs[(nd * 16 + lr) * 264 + kk * 32 + lq * 8]);
                oacc[nd] = __builtin_amdgcn_mfma_f32_16x16x32_bf16(ap, bv, oacc[nd], 0, 0, 0);
            }
        }
    }

#pragma unroll
    for (int r = 0; r < 4; r++) {
        float inv = 1.0f / l4[r];
        long rowg = (long)b * T + trow0 + r;
#pragma unroll
        for (int nd = 0; nd < 4; nd++) {
            o[rowg * E + h * 64 + nd * 16 + lr] = (bf16)(oacc[nd][r] * inv);
        }
    }
}

// ---------------- layernorm: bf16 in -> bf16 out (wave per row, bf16x8) ----------------
__global__ void k_ln(const bf16* __restrict__ x, const float* __restrict__ g,
                     const float* __restrict__ b, bf16* __restrict__ h) {
    int row = blockIdx.x * 4 + (threadIdx.x >> 6);
    int lane = threadIdx.x & 63;
    const bf16* xr = x + (long)row * E;
    float v[8];
    float s = 0.f;
    if (lane < 48) {
        bf16x8 pack = *(const bf16x8*)(xr + lane * 8);
#pragma unroll
        for (int i = 0; i < 8; i++) { v[i] = (float)pack[i]; s += v[i]; }
    } else {
#pragma unroll
        for (int i = 0; i < 8; i++) v[i] = 0.f;
    }
#pragma unroll
    for (int o = 1; o < 64; o <<= 1) s += __shfl_xor(s, o, 64);
    float mu = s * (1.0f / E);
    float q = 0.f;
    if (lane < 48) {
#pragma unroll
        for (int i = 0; i < 8; i++) { float d = v[i] - mu; q += d * d; }
    }
#pragma unroll
    for (int o = 1; o < 64; o <<= 1) q += __shfl_xor(q, o, 64);
    float rs = rsqrtf(q * (1.0f / E) + 1e-5f);
    if (lane < 48) {
        bf16x8 out;
#pragma unroll
        for (int i = 0; i < 8; i++) {
            int c = lane * 8 + i;
            out[i] = (bf16)((v[i] - mu) * rs * g[c] + b[c]);
        }
        *(bf16x8*)(h + (long)row * E + lane * 8) = out;
    }
}

// ---------------- fragment-layout weight transpose ----------------
// W [L][K][N] (f32) -> Wf [L][NPAD/16][K/32][64][8] (bf16), cols>=N zero.
// Wf[((c16*nks + ks)*64 + lane)*8 + j] = W[ks*32 + (lane>>4)*8 + j][c16*16 + (lane&15)]
__global__ void k_transpose_frag(const float* __restrict__ W, bf16* __restrict__ Wf,
                                 int K, int N, int NPAD) {
    long idx = (long)blockIdx.x * 256 + threadIdx.x;   // over NL*NPAD*K
    long per = (long)NPAD * K;
    int l = (int)(idx / per);
    long r = idx - (long)l * per;
    int j = (int)(r & 7); r >>= 3;
    int lane = (int)(r & 63); r >>= 6;
    int nks = K / 32;
    int ks = (int)(r % nks);
    int c16 = (int)(r / nks);
    int col = c16 * 16 + (lane & 15);
    int k = ks * 32 + (lane >> 4) * 8 + j;
    Wf[idx] = (col < N) ? (bf16)W[((long)l * K + k) * N + col] : (bf16)0.0f;
}

// ---------------- fragment-layout fused QKV transpose: [L] cols 0..1151 ----------------
__global__ void k_transpose_qkv_frag(const float* __restrict__ Wq, const float* __restrict__ Wk,
                                     const float* __restrict__ Wv, bf16* __restrict__ Wf) {
    long idx = (long)blockIdx.x * 256 + threadIdx.x;   // over NL*1152*384
    long per = (long)1152 * E;
    int l = (int)(idx / per);
    long r = idx - (long)l * per;
    int j = (int)(r & 7); r >>= 3;
    int lane = (int)(r & 63); r >>= 6;
    int nks = E / 32;                                   // 12
    int ks = (int)(r % nks);
    int c16 = (int)(r / nks);
    int col = c16 * 16 + (lane & 15);                   // 0..1151
    int k = ks * 32 + (lane >> 4) * 8 + j;
    const float* src;
    int cc;
    if (col < 384)      { src = Wq; cc = col; }
    else if (col < 768) { src = Wk; cc = col - 384; }
    else                { src = Wv; cc = col - 768; }
    Wf[idx] = (bf16)src[((long)l * E + k) * E + cc];
}

// ---------------- fused QKV bias concat: [L][1152] f32 ----------------
__global__ void k_bias_qkv(const float* __restrict__ bq, const float* __restrict__ bk,
                           const float* __restrict__ bv, float* __restrict__ bqkv) {
    int idx = blockIdx.x * 256 + threadIdx.x;
    int l = idx / 1152;
    int j = idx - l * 1152;
    const float* src;
    int jj;
    if (j < 384)      { src = bq; jj = j; }
    else if (j < 768) { src = bk; jj = j - 384; }
    else              { src = bv; jj = j - 768; }
    bqkv[idx] = src[l * E + jj];
}

// ---------------- embedding + positional -> bf16 residual ----------------
__global__ void k_embed(const int* __restrict__ tokens, const float* __restrict__ pos,
                        const float* __restrict__ emb, bf16* __restrict__ x) {
    long idx = (long)blockIdx.x * 256 + threadIdx.x;
    int e = (int)(idx % E);
    long bt = idx / E;
    int t = (int)(bt % T);
    int tok = tokens[bt];
    x[idx] = (bf16)(emb[(long)tok * E + e] + pos[(long)t * E + e]);
}

// ---------------- launcher ----------------
extern "C" void kernel_launch(void* const* d_in, const int* in_sizes, int n_in,
                              void* d_out, int out_size, void* d_ws, size_t ws_size,
                              hipStream_t stream) {
    const int*   tokens = (const int*)d_in[0];
    const float* pos  = (const float*)d_in[1];
    const float* emb  = (const float*)d_in[2];
    const float* Wq   = (const float*)d_in[3];
    const float* bq   = (const float*)d_in[4];
    const float* Wk   = (const float*)d_in[5];
    const float* bk   = (const float*)d_in[6];
    const float* Wv   = (const float*)d_in[7];
    const float* bv   = (const float*)d_in[8];
    const float* Wo   = (const float*)d_in[9];
    const float* bo   = (const float*)d_in[10];
    const float* g1   = (const float*)d_in[11];
    const float* be1  = (const float*)d_in[12];
    const float* W1   = (const float*)d_in[13];
    const float* c1   = (const float*)d_in[14];
    const float* W2   = (const float*)d_in[15];
    const float* c2   = (const float*)d_in[16];
    const float* g2   = (const float*)d_in[17];
    const float* be2  = (const float*)d_in[18];
    const float* Wl   = (const float*)d_in[19];
    const float* bl   = (const float*)d_in[20];

    // ---- workspace layout (~173 MB peak) ----
    char* p = (char*)d_ws;
    bf16* x  = (bf16*)p;   p += (long)MTOT * E * 2;          // residual (bf16)
    bf16* h  = (bf16*)p;   p += (long)MTOT * E * 2;          // LN out / o (alias)
    bf16* qk = (bf16*)p;   p += (long)MTOT * 768 * 2;        // fused Q|K
    bf16* vt = (bf16*)p;   p += (long)BB * E * T * 2;        // V^T per (seq,head)
    bf16* SP = (bf16*)p;   p += (long)CB * NH * T * T * 2;   // mid alias span
    bf16* WqkvF = (bf16*)p; p += (long)NL * 1152 * E * 2;    // fragment layouts
    bf16* WoF = (bf16*)p;  p += (long)NL * E * E * 2;
    bf16* W1F = (bf16*)p;  p += (long)NL * DFF * E * 2;
    bf16* W2F = (bf16*)p;  p += (long)NL * E * DFF * 2;
    bf16* WlF = (bf16*)p;  p += (long)128 * E * 2;
    float* bqkv = (float*)p; p += (long)NL * 1152 * 4;
    bf16* mid = qk;          // alias: qk+vt+SP = MTOT*DFF*2 exactly
    bf16* o   = h;
    (void)SP;

    // ---- setup (once per call) ----
    k_transpose_qkv_frag<<<(NL * 1152 * E) / 256, 256, 0, stream>>>(Wq, Wk, Wv, WqkvF);
    k_transpose_frag<<<(NL * E * E) / 256, 256, 0, stream>>>(Wo, WoF, E, E, E);
    k_transpose_frag<<<(NL * DFF * E) / 256, 256, 0, stream>>>(W1, W1F, E, DFF, DFF);
    k_transpose_frag<<<(NL * E * DFF) / 256, 256, 0, stream>>>(W2, W2F, DFF, E, E);
    k_transpose_frag<<<(128 * E) / 256, 256, 0, stream>>>(Wl, WlF, E, NV, 128);
    k_bias_qkv<<<(NL * 1152) / 256, 256, 0, stream>>>(bq, bk, bv, bqkv);

    // ---- embedding ----
    k_embed<<<(MTOT * E) / 256, 256, 0, stream>>>(tokens, pos, emb, x);

    for (int l = 0; l < NL; l++) {
        // LN1
        k_ln<<<MTOT / 4, 256, 0, stream>>>(x, g1 + l * E, be1 + l * E, h);
        // fused QKV: M=32768, N=1152, K=384 — W=4: 2304 blocks = 3 exact
        // rounds of 768 concurrent (3 blocks/CU at 48KB LDS)
        k_gemm<5, 4><<<256 * 9, 256, 0, stream>>>(h, E, WqkvF + (long)l * 1152 * E,
                                                  bqkv + l * 1152, qk, vt, 0,
                                                  256, 9, 1152, E, 0);
        // fused causal attention
        k_attn<<<BB * NH * 4, 256, 0, stream>>>(qk, vt, o);
        // x += O @ Wo + bo
        k_gemm<1, 4><<<256 * 3, 256, 0, stream>>>(o, E, WoF + (long)l * E * E,
                                                  bo + l * E, x, nullptr, E,
                                                  256, 3, E, E, 0);
        // LN2
        k_ln<<<MTOT / 4, 256, 0, stream>>>(x, g2 + l * E, be2 + l * E, h);
        // mid = relu(h @ W1 + c1)  — W=8: 1536 blocks = 3 exact rounds
        k_gemm<0, 8><<<128 * 12, 512, 0, stream>>>(h, E, W1F + (long)l * DFF * E,
                                                   c1 + l * DFF, mid, nullptr, DFF,
                                                   128, 12, DFF, E, 1);
        // x += mid @ W2 + c2
        k_gemm<1, 4><<<256 * 3, 256, 0, stream>>>(mid, DFF, W2F + (long)l * E * DFF,
                                                  c2 + l * E, x, nullptr, E,
                                                  256, 3, E, DFF, 0);
    }

    // logits = x @ Wl + bl  (N=65 masked from 128), f32 out
    k_gemm<4, 4><<<256 * 1, 256, 0, stream>>>(x, E, WlF,
                                              bl, d_out, nullptr, NV,
                                              256, 1, NV, E, 0);
}